// Round 1
// baseline (537.454 us; speedup 1.0000x reference)
//
#include <hip/hip_runtime.h>
#include <math.h>
#include <stdint.h>

typedef __attribute__((ext_vector_type(8)))  short   short8;
typedef __attribute__((ext_vector_type(4)))  short   short4v;
typedef __attribute__((ext_vector_type(8)))  __bf16  bf16x8;
typedef __attribute__((ext_vector_type(4)))  float   f32x4;

__device__ __forceinline__ unsigned short f2b(float f) {
    union { float f; unsigned u; } v; v.f = f;
    unsigned r = v.u + 0x7FFF + ((v.u >> 16) & 1);
    return (unsigned short)(r >> 16);
}

__device__ __forceinline__ f32x4 mfma_bf16(bf16x8 a, bf16x8 b, f32x4 c) {
    return __builtin_amdgcn_mfma_f32_16x16x32_bf16(a, b, c, 0, 0, 0);
}

__device__ __forceinline__ void gload_lds16(const unsigned short* g, unsigned short* l) {
    __builtin_amdgcn_global_load_lds(
        (const __attribute__((address_space(1))) void*)g,
        (__attribute__((address_space(3))) void*)l,
        16, 0, 0);
}

// ---------------- weight transpose + f32->bf16 ----------------
__global__ __launch_bounds__(256) void wconv_t(const float* __restrict__ W,
                                               unsigned short* __restrict__ Wt,
                                               int K, int N) {
    __shared__ float tile[32][33];
    int bk = blockIdx.x * 32;
    int bn = blockIdx.y * 32;
    int tx = threadIdx.x & 31, ty = threadIdx.x >> 5;  // 32 x 8
#pragma unroll
    for (int i = 0; i < 4; ++i) {
        int r = ty + i * 8;
        tile[r][tx] = W[(size_t)(bk + r) * N + bn + tx];
    }
    __syncthreads();
#pragma unroll
    for (int i = 0; i < 4; ++i) {
        int r = ty + i * 8;
        Wt[(size_t)(bn + r) * K + bk + tx] = f2b(tile[tx][r]);
    }
}

// ---------------- f32 -> bf16 elementwise (x4) ----------------
__global__ __launch_bounds__(256) void fconv(const float* __restrict__ in,
                                             unsigned short* __restrict__ out, int n4) {
    int i = blockIdx.x * 256 + threadIdx.x;
    if (i >= n4) return;
    f32x4 v = ((const f32x4*)in)[i];
    short4v o;
    o.x = (short)f2b(v.x); o.y = (short)f2b(v.y);
    o.z = (short)f2b(v.z); o.w = (short)f2b(v.w);
    ((short4v*)out)[i] = o;
}

// ---------------- layernorm (C=1024), f32 in -> bf16 out ----------------
__global__ __launch_bounds__(256) void lnorm(const float* __restrict__ x,
                                             const float* __restrict__ g,
                                             const float* __restrict__ bta,
                                             unsigned short* __restrict__ out) {
    int row = blockIdx.x;
    const f32x4* xr = (const f32x4*)(x + (size_t)row * 1024);
    int t = threadIdx.x;
    f32x4 v = xr[t];
    float s  = v.x + v.y + v.z + v.w;
    float s2 = v.x * v.x + v.y * v.y + v.z * v.z + v.w * v.w;
#pragma unroll
    for (int m = 1; m < 64; m <<= 1) {
        s  += __shfl_xor(s, m);
        s2 += __shfl_xor(s2, m);
    }
    __shared__ float rs[8];
    int w = t >> 6;
    if ((t & 63) == 0) { rs[w] = s; rs[4 + w] = s2; }
    __syncthreads();
    s  = rs[0] + rs[1] + rs[2] + rs[3];
    s2 = rs[4] + rs[5] + rs[6] + rs[7];
    float mean = s * (1.0f / 1024.0f);
    float var  = s2 * (1.0f / 1024.0f) - mean * mean;
    float rstd = rsqrtf(var + 1e-5f);
    f32x4 gv = ((const f32x4*)g)[t];
    f32x4 bv = ((const f32x4*)bta)[t];
    short4v o;
    o.x = (short)f2b((v.x - mean) * rstd * gv.x + bv.x);
    o.y = (short)f2b((v.y - mean) * rstd * gv.y + bv.y);
    o.z = (short)f2b((v.z - mean) * rstd * gv.z + bv.z);
    o.w = (short)f2b((v.w - mean) * rstd * gv.w + bv.w);
    ((short4v*)(out + (size_t)row * 1024))[t] = o;
}

// ---------------- GEMM: A[M,K] bf16 x Bt[N,K] bf16 -> C[M,N] ----------------
// EPI: 0 = bf16 out (optional q-scale on cols < scale_cols)
//      1 = bf16 out, +bias, exact GELU
//      2 = f32 out, +bias, +f32 residual
template <int EPI, bool SCALE_Q>
__global__ __launch_bounds__(256) void gemm_bt(const unsigned short* __restrict__ A,
                                               const unsigned short* __restrict__ Bt,
                                               void* __restrict__ C,
                                               const float* __restrict__ bias,
                                               const float* __restrict__ resid,
                                               int M, int N, int K, int scale_cols) {
    const int m0 = blockIdx.x * 128;
    const int n0 = blockIdx.y * 128;
    __shared__ unsigned short As[128 * 64];
    __shared__ unsigned short Bs[128 * 64];
    const int tid  = threadIdx.x;
    const int lane = tid & 63;
    const int wid  = tid >> 6;
    const int wm = wid >> 1, wn = wid & 1;  // 2x2 waves, 64x64 each

    f32x4 acc[4][4] = {};

    const int srow = tid >> 3;        // 0..31
    const int scol = (tid & 7) * 8;   // element col

    for (int k0 = 0; k0 < K; k0 += 64) {
#pragma unroll
        for (int i = 0; i < 4; ++i)
            gload_lds16(A + (size_t)(m0 + srow + i * 32) * K + k0 + scol,
                        &As[(srow + i * 32) * 64 + scol]);
#pragma unroll
        for (int i = 0; i < 4; ++i)
            gload_lds16(Bt + (size_t)(n0 + srow + i * 32) * K + k0 + scol,
                        &Bs[(srow + i * 32) * 64 + scol]);
        __syncthreads();
#pragma unroll
        for (int kk = 0; kk < 2; ++kk) {
            const int ko = kk * 32 + (lane >> 4) * 8;
            bf16x8 a[4], b[4];
#pragma unroll
            for (int mi = 0; mi < 4; ++mi)
                a[mi] = *(const bf16x8*)&As[(wm * 64 + mi * 16 + (lane & 15)) * 64 + ko];
#pragma unroll
            for (int ni = 0; ni < 4; ++ni)
                b[ni] = *(const bf16x8*)&Bs[(wn * 64 + ni * 16 + (lane & 15)) * 64 + ko];
#pragma unroll
            for (int mi = 0; mi < 4; ++mi)
#pragma unroll
                for (int ni = 0; ni < 4; ++ni)
                    acc[mi][ni] = mfma_bf16(a[mi], b[ni], acc[mi][ni]);
        }
        __syncthreads();
    }

    const int rbase = m0 + wm * 64 + (lane >> 4) * 4;
    const int cbase = n0 + wn * 64 + (lane & 15);
#pragma unroll
    for (int mi = 0; mi < 4; ++mi) {
#pragma unroll
        for (int r = 0; r < 4; ++r) {
            const int row = rbase + mi * 16 + r;
#pragma unroll
            for (int ni = 0; ni < 4; ++ni) {
                const int col = cbase + ni * 16;
                float v = acc[mi][ni][r];
                if (EPI == 0) {
                    if (SCALE_Q && col < scale_cols) v *= 0.125f;
                    ((unsigned short*)C)[(size_t)row * N + col] = f2b(v);
                } else if (EPI == 1) {
                    v += bias[col];
                    v = 0.5f * v * (1.0f + erff(v * 0.70710678118f));
                    ((unsigned short*)C)[(size_t)row * N + col] = f2b(v);
                } else {
                    v += bias[col] + resid[(size_t)row * N + col];
                    ((float*)C)[(size_t)row * N + col] = v;
                }
            }
        }
    }
}

// ---------------- V transpose: [b,n, col_off + h*64 + d] -> Vt[bh][d][n] ----------------
__global__ __launch_bounds__(256) void vtrans(const unsigned short* __restrict__ src,
                                              unsigned short* __restrict__ dst,
                                              int src_stride, int col_off) {
    int n0 = blockIdx.x * 64;
    int bh = blockIdx.y;
    int b = bh >> 4, h = bh & 15;
    __shared__ unsigned short t[64][65];
    int tx = threadIdx.x & 63, ty = threadIdx.x >> 6;  // 64 x 4
    const unsigned short* s = src + (size_t)(b * 2048 + n0) * src_stride + col_off + h * 64;
#pragma unroll
    for (int i = 0; i < 16; ++i) {
        int n = ty * 16 + i;
        t[n][tx] = s[(size_t)n * src_stride + tx];
    }
    __syncthreads();
    unsigned short* d = dst + (size_t)bh * 64 * 2048 + n0;
#pragma unroll
    for (int i = 0; i < 16; ++i) {
        int dd = ty * 16 + i;
        d[(size_t)dd * 2048 + tx] = t[tx][dd];
    }
}

// ---------------- flash attention, D=64, N=2048, QBLK=64, KVB=64 ----------------
__global__ __launch_bounds__(256) void attn(const unsigned short* __restrict__ Q, int q_stride, int q_off,
                                            const unsigned short* __restrict__ Kp, int k_stride, int k_off,
                                            const unsigned short* __restrict__ Vt,
                                            const float* __restrict__ res,
                                            float* __restrict__ out) {
    const int qt = blockIdx.x;   // 0..31
    const int bh = blockIdx.y;   // 0..31
    const int b = bh >> 4, h = bh & 15;
    const int lane = threadIdx.x & 63, w = threadIdx.x >> 6;

    __shared__ unsigned short Ks[64][72];
    __shared__ unsigned short Vs[64][72];
    __shared__ unsigned short Ps[4][16][72];

    // per-wave Q fragments (16 q-rows, D=64)
    const int qrow = qt * 64 + w * 16 + (lane & 15);
    const unsigned short* qp = Q + (size_t)(b * 2048 + qrow) * q_stride + q_off + h * 64;
    bf16x8 qf0 = *(const bf16x8*)&qp[(lane >> 4) * 8];
    bf16x8 qf1 = *(const bf16x8*)&qp[32 + (lane >> 4) * 8];

    f32x4 oacc[4] = {};
    float mrow[4], lrow[4];
#pragma unroll
    for (int r = 0; r < 4; ++r) { mrow[r] = -1e30f; lrow[r] = 0.f; }

    const unsigned short* kbase = Kp + (size_t)(b * 2048) * k_stride + k_off + h * 64;
    const unsigned short* vbase = Vt + (size_t)bh * 64 * 2048;

    const int srow = threadIdx.x >> 3;       // 0..31
    const int scol = (threadIdx.x & 7) * 8;  // 0..56

    for (int n0 = 0; n0 < 2048; n0 += 64) {
        // stage K [j][d] and V^T [d][j] tiles (reg-staged, padded LDS)
#pragma unroll
        for (int i = 0; i < 2; ++i) {
            int rr = srow + i * 32;
            short8 kv8 = *(const short8*)&kbase[(size_t)(n0 + rr) * k_stride + scol];
            *(short8*)&Ks[rr][scol] = kv8;
            short8 vv8 = *(const short8*)&vbase[(size_t)rr * 2048 + n0 + scol];
            *(short8*)&Vs[rr][scol] = vv8;
        }
        __syncthreads();

        // S = Q K^T for this wave's 16 q-rows
        f32x4 s[4];
#pragma unroll
        for (int js = 0; js < 4; ++js) {
            bf16x8 kf0 = *(const bf16x8*)&Ks[js * 16 + (lane & 15)][(lane >> 4) * 8];
            bf16x8 kf1 = *(const bf16x8*)&Ks[js * 16 + (lane & 15)][32 + (lane >> 4) * 8];
            f32x4 t = {};
            t = mfma_bf16(qf0, kf0, t);
            t = mfma_bf16(qf1, kf1, t);
            s[js] = t;
        }

        // online softmax (rows q = (lane>>4)*4 + r, cols across 16-lane group)
#pragma unroll
        for (int r = 0; r < 4; ++r) {
            float mx = fmaxf(fmaxf(s[0][r], s[1][r]), fmaxf(s[2][r], s[3][r]));
#pragma unroll
            for (int msk = 1; msk < 16; msk <<= 1) mx = fmaxf(mx, __shfl_xor(mx, msk));
            float mnew = fmaxf(mrow[r], mx);
            float al = __expf(mrow[r] - mnew);
            mrow[r] = mnew;
            float ssum = 0.f;
#pragma unroll
            for (int js = 0; js < 4; ++js) {
                float p = __expf(s[js][r] - mnew);
                s[js][r] = p;
                ssum += p;
            }
#pragma unroll
            for (int msk = 1; msk < 16; msk <<= 1) ssum += __shfl_xor(ssum, msk);
            lrow[r] = lrow[r] * al + ssum;
#pragma unroll
            for (int ds = 0; ds < 4; ++ds) oacc[ds][r] *= al;
            const int q_local = (lane >> 4) * 4 + r;
#pragma unroll
            for (int js = 0; js < 4; ++js)
                Ps[w][q_local][js * 16 + (lane & 15)] = f2b(s[js][r]);
        }

        // O += P V
#pragma unroll
        for (int jc = 0; jc < 2; ++jc) {
            bf16x8 pf = *(const bf16x8*)&Ps[w][lane & 15][jc * 32 + (lane >> 4) * 8];
#pragma unroll
            for (int ds = 0; ds < 4; ++ds) {
                bf16x8 vf = *(const bf16x8*)&Vs[ds * 16 + (lane & 15)][jc * 32 + (lane >> 4) * 8];
                oacc[ds] = mfma_bf16(pf, vf, oacc[ds]);
            }
        }
        __syncthreads();
    }

    // epilogue: O / l + residual
#pragma unroll
    for (int r = 0; r < 4; ++r) {
        const int row = b * 2048 + qt * 64 + w * 16 + (lane >> 4) * 4 + r;
        const float inv = 1.0f / lrow[r];
#pragma unroll
        for (int ds = 0; ds < 4; ++ds) {
            const int col = h * 64 + ds * 16 + (lane & 15);
            const size_t idx = (size_t)row * 1024 + col;
            out[idx] = oacc[ds][r] * inv + res[idx];
        }
    }
}

// ---------------- host ----------------
extern "C" void kernel_launch(void* const* d_in, const int* in_sizes, int n_in,
                              void* d_out, int out_size, void* d_ws, size_t ws_size,
                              hipStream_t stream) {
    const float* x      = (const float*)d_in[0];
    const float* feat   = (const float*)d_in[1];
    const float* norm_g = (const float*)d_in[2];
    const float* norm_b = (const float*)d_in[3];
    const float* W_cq   = (const float*)d_in[4];
    const float* W_ckv  = (const float*)d_in[5];
    const float* W_sqkv = (const float*)d_in[6];
    const float* ffn_g  = (const float*)d_in[7];
    const float* ffn_b  = (const float*)d_in[8];
    const float* W1     = (const float*)d_in[9];
    const float* b1     = (const float*)d_in[10];
    const float* W2     = (const float*)d_in[11];
    const float* b2     = (const float*)d_in[12];
    float* out = (float*)d_out;

    char* ws = (char*)d_ws;
    unsigned short* wq_t   = (unsigned short*)(ws + (size_t)(0u)   * (1u << 20));  // 2MB
    unsigned short* wkv_t  = (unsigned short*)(ws + (size_t)(2u)   * (1u << 20));  // 1.5MB
    unsigned short* wqkv_t = (unsigned short*)(ws + (size_t)(4u)   * (1u << 20));  // 6MB
    unsigned short* w1_t   = (unsigned short*)(ws + (size_t)(10u)  * (1u << 20));  // 8MB
    unsigned short* w2_t   = (unsigned short*)(ws + (size_t)(18u)  * (1u << 20));  // 8MB
    unsigned short* featb  = (unsigned short*)(ws + (size_t)(26u)  * (1u << 20));  // 3MB
    unsigned short* t0     = (unsigned short*)(ws + (size_t)(29u)  * (1u << 20));  // 8MB
    float*          cross  = (float*)        (ws + (size_t)(37u)  * (1u << 20));   // 16MB
    unsigned short* qb     = (unsigned short*)(ws + (size_t)(53u)  * (1u << 20));  // 8MB
    unsigned short* kvb    = (unsigned short*)(ws + (size_t)(61u)  * (1u << 20));  // 16MB
    unsigned short* qkvb   = (unsigned short*)(ws + (size_t)(77u)  * (1u << 20));  // 24MB
    unsigned short* vtb    = (unsigned short*)(ws + (size_t)(101u) * (1u << 20));  // 8MB
    unsigned short* h1     = (unsigned short*)(ws + (size_t)(53u)  * (1u << 20));  // 32MB (aliases q/kv/qkv, dead by FFN)

    // weights -> bf16 transposed [N,K]
    wconv_t<<<dim3(1024 / 32, 1024 / 32), 256, 0, stream>>>(W_cq,   wq_t,   1024, 1024);
    wconv_t<<<dim3(384 / 32,  2048 / 32), 256, 0, stream>>>(W_ckv,  wkv_t,  384,  2048);
    wconv_t<<<dim3(1024 / 32, 3072 / 32), 256, 0, stream>>>(W_sqkv, wqkv_t, 1024, 3072);
    wconv_t<<<dim3(1024 / 32, 4096 / 32), 256, 0, stream>>>(W1,     w1_t,   1024, 4096);
    wconv_t<<<dim3(4096 / 32, 1024 / 32), 256, 0, stream>>>(W2,     w2_t,   4096, 1024);
    fconv<<<dim3((4096 * 384 / 4) / 256), 256, 0, stream>>>(feat, featb, 4096 * 384 / 4);

    // ---- cross attention ----
    lnorm<<<4096, 256, 0, stream>>>(x, norm_g, norm_b, t0);
    gemm_bt<0, true ><<<dim3(32, 8),  256, 0, stream>>>(t0,    wq_t,  qb,  nullptr, nullptr, 4096, 1024, 1024, 1024);
    gemm_bt<0, false><<<dim3(32, 16), 256, 0, stream>>>(featb, wkv_t, kvb, nullptr, nullptr, 4096, 2048, 384,  0);
    vtrans<<<dim3(32, 32), 256, 0, stream>>>(kvb, vtb, 2048, 1024);
    attn<<<dim3(32, 32), 256, 0, stream>>>(qb, 1024, 0, kvb, 2048, 0, vtb, x, cross);

    // ---- self attention ----
    lnorm<<<4096, 256, 0, stream>>>(cross, norm_g, norm_b, t0);
    gemm_bt<0, true ><<<dim3(32, 24), 256, 0, stream>>>(t0, wqkv_t, qkvb, nullptr, nullptr, 4096, 3072, 1024, 1024);
    vtrans<<<dim3(32, 32), 256, 0, stream>>>(qkvb, vtb, 3072, 2048);
    attn<<<dim3(32, 32), 256, 0, stream>>>(qkvb, 3072, 0, qkvb, 3072, 1024, vtb, cross, out);

    // ---- FFN ----
    lnorm<<<4096, 256, 0, stream>>>(out, ffn_g, ffn_b, t0);
    gemm_bt<1, false><<<dim3(32, 32), 256, 0, stream>>>(t0, w1_t, h1, b1, nullptr, 4096, 4096, 1024, 0);
    gemm_bt<2, false><<<dim3(32, 8),  256, 0, stream>>>(h1, w2_t, out, b2, (const float*)out, 4096, 1024, 4096, 0);
}

// Round 2
// 537.359 us; speedup vs baseline: 1.0002x; 1.0002x over previous
//
#include <hip/hip_runtime.h>
#include <math.h>
#include <stdint.h>

typedef __attribute__((ext_vector_type(8)))  short   short8;
typedef __attribute__((ext_vector_type(4)))  short   short4v;
typedef __attribute__((ext_vector_type(8)))  __bf16  bf16x8;
typedef __attribute__((ext_vector_type(4)))  float   f32x4;
typedef __attribute__((ext_vector_type(16))) float   f32x16;

__device__ __forceinline__ unsigned short f2b(float f) {
    union { float f; unsigned u; } v; v.f = f;
    unsigned r = v.u + 0x7FFF + ((v.u >> 16) & 1);
    return (unsigned short)(r >> 16);
}

__device__ __forceinline__ f32x4 mfma_bf16(bf16x8 a, bf16x8 b, f32x4 c) {
    return __builtin_amdgcn_mfma_f32_16x16x32_bf16(a, b, c, 0, 0, 0);
}

__device__ __forceinline__ f32x16 mfma32(bf16x8 a, bf16x8 b, f32x16 c) {
    return __builtin_amdgcn_mfma_f32_32x32x16_bf16(a, b, c, 0, 0, 0);
}

__device__ __forceinline__ unsigned cvt_pk_bf16(float lo, float hi) {
    unsigned r;
    asm volatile("v_cvt_pk_bf16_f32 %0, %1, %2" : "=v"(r) : "v"(lo), "v"(hi));
    return r;
}

__device__ __forceinline__ void gload_lds16(const unsigned short* g, unsigned short* l) {
    __builtin_amdgcn_global_load_lds(
        (const __attribute__((address_space(1))) void*)g,
        (__attribute__((address_space(3))) void*)l,
        16, 0, 0);
}

// 0.125 (d_head^-0.5) * log2(e): softmax computed in base-2 (exact rescale)
#define QSCALE 0.18033688011112042592f

// ---------------- weight transpose + f32->bf16 ----------------
__global__ __launch_bounds__(256) void wconv_t(const float* __restrict__ W,
                                               unsigned short* __restrict__ Wt,
                                               int K, int N) {
    __shared__ float tile[32][33];
    int bk = blockIdx.x * 32;
    int bn = blockIdx.y * 32;
    int tx = threadIdx.x & 31, ty = threadIdx.x >> 5;  // 32 x 8
#pragma unroll
    for (int i = 0; i < 4; ++i) {
        int r = ty + i * 8;
        tile[r][tx] = W[(size_t)(bk + r) * N + bn + tx];
    }
    __syncthreads();
#pragma unroll
    for (int i = 0; i < 4; ++i) {
        int r = ty + i * 8;
        Wt[(size_t)(bn + r) * K + bk + tx] = f2b(tile[tx][r]);
    }
}

// ---------------- f32 -> bf16 elementwise (x4) ----------------
__global__ __launch_bounds__(256) void fconv(const float* __restrict__ in,
                                             unsigned short* __restrict__ out, int n4) {
    int i = blockIdx.x * 256 + threadIdx.x;
    if (i >= n4) return;
    f32x4 v = ((const f32x4*)in)[i];
    short4v o;
    o.x = (short)f2b(v.x); o.y = (short)f2b(v.y);
    o.z = (short)f2b(v.z); o.w = (short)f2b(v.w);
    ((short4v*)out)[i] = o;
}

// ---------------- layernorm (C=1024), f32 in -> bf16 out ----------------
__global__ __launch_bounds__(256) void lnorm(const float* __restrict__ x,
                                             const float* __restrict__ g,
                                             const float* __restrict__ bta,
                                             unsigned short* __restrict__ out) {
    int row = blockIdx.x;
    const f32x4* xr = (const f32x4*)(x + (size_t)row * 1024);
    int t = threadIdx.x;
    f32x4 v = xr[t];
    float s  = v.x + v.y + v.z + v.w;
    float s2 = v.x * v.x + v.y * v.y + v.z * v.z + v.w * v.w;
#pragma unroll
    for (int m = 1; m < 64; m <<= 1) {
        s  += __shfl_xor(s, m);
        s2 += __shfl_xor(s2, m);
    }
    __shared__ float rs[8];
    int w = t >> 6;
    if ((t & 63) == 0) { rs[w] = s; rs[4 + w] = s2; }
    __syncthreads();
    s  = rs[0] + rs[1] + rs[2] + rs[3];
    s2 = rs[4] + rs[5] + rs[6] + rs[7];
    float mean = s * (1.0f / 1024.0f);
    float var  = s2 * (1.0f / 1024.0f) - mean * mean;
    float rstd = rsqrtf(var + 1e-5f);
    f32x4 gv = ((const f32x4*)g)[t];
    f32x4 bv = ((const f32x4*)bta)[t];
    short4v o;
    o.x = (short)f2b((v.x - mean) * rstd * gv.x + bv.x);
    o.y = (short)f2b((v.y - mean) * rstd * gv.y + bv.y);
    o.z = (short)f2b((v.z - mean) * rstd * gv.z + bv.z);
    o.w = (short)f2b((v.w - mean) * rstd * gv.w + bv.w);
    ((short4v*)(out + (size_t)row * 1024))[t] = o;
}

// ---------------- GEMM: A[M,K] bf16 x Bt[N,K] bf16 -> C[M,N] ----------------
// EPI: 0 = bf16 out (optional q-scale on cols < scale_cols)
//      1 = bf16 out, +bias, exact GELU
//      2 = f32 out, +bias, +f32 residual
template <int EPI, bool SCALE_Q>
__global__ __launch_bounds__(256) void gemm_bt(const unsigned short* __restrict__ A,
                                               const unsigned short* __restrict__ Bt,
                                               void* __restrict__ C,
                                               const float* __restrict__ bias,
                                               const float* __restrict__ resid,
                                               int M, int N, int K, int scale_cols) {
    const int m0 = blockIdx.x * 128;
    const int n0 = blockIdx.y * 128;
    __shared__ unsigned short As[128 * 64];
    __shared__ unsigned short Bs[128 * 64];
    const int tid  = threadIdx.x;
    const int lane = tid & 63;
    const int wid  = tid >> 6;
    const int wm = wid >> 1, wn = wid & 1;  // 2x2 waves, 64x64 each

    f32x4 acc[4][4] = {};

    const int srow = tid >> 3;        // 0..31
    const int scol = (tid & 7) * 8;   // element col

    for (int k0 = 0; k0 < K; k0 += 64) {
#pragma unroll
        for (int i = 0; i < 4; ++i)
            gload_lds16(A + (size_t)(m0 + srow + i * 32) * K + k0 + scol,
                        &As[(srow + i * 32) * 64 + scol]);
#pragma unroll
        for (int i = 0; i < 4; ++i)
            gload_lds16(Bt + (size_t)(n0 + srow + i * 32) * K + k0 + scol,
                        &Bs[(srow + i * 32) * 64 + scol]);
        __syncthreads();
#pragma unroll
        for (int kk = 0; kk < 2; ++kk) {
            const int ko = kk * 32 + (lane >> 4) * 8;
            bf16x8 a[4], b[4];
#pragma unroll
            for (int mi = 0; mi < 4; ++mi)
                a[mi] = *(const bf16x8*)&As[(wm * 64 + mi * 16 + (lane & 15)) * 64 + ko];
#pragma unroll
            for (int ni = 0; ni < 4; ++ni)
                b[ni] = *(const bf16x8*)&Bs[(wn * 64 + ni * 16 + (lane & 15)) * 64 + ko];
#pragma unroll
            for (int mi = 0; mi < 4; ++mi)
#pragma unroll
                for (int ni = 0; ni < 4; ++ni)
                    acc[mi][ni] = mfma_bf16(a[mi], b[ni], acc[mi][ni]);
        }
        __syncthreads();
    }

    const int rbase = m0 + wm * 64 + (lane >> 4) * 4;
    const int cbase = n0 + wn * 64 + (lane & 15);
#pragma unroll
    for (int mi = 0; mi < 4; ++mi) {
#pragma unroll
        for (int r = 0; r < 4; ++r) {
            const int row = rbase + mi * 16 + r;
#pragma unroll
            for (int ni = 0; ni < 4; ++ni) {
                const int col = cbase + ni * 16;
                float v = acc[mi][ni][r];
                if (EPI == 0) {
                    if (SCALE_Q && col < scale_cols) v *= QSCALE;
                    ((unsigned short*)C)[(size_t)row * N + col] = f2b(v);
                } else if (EPI == 1) {
                    v += bias[col];
                    v = 0.5f * v * (1.0f + erff(v * 0.70710678118f));
                    ((unsigned short*)C)[(size_t)row * N + col] = f2b(v);
                } else {
                    v += bias[col] + resid[(size_t)row * N + col];
                    ((float*)C)[(size_t)row * N + col] = v;
                }
            }
        }
    }
}

// ---------------- V transpose: [b,n, col_off + h*64 + d] -> Vt[bh][d][n] ----------------
__global__ __launch_bounds__(256) void vtrans(const unsigned short* __restrict__ src,
                                              unsigned short* __restrict__ dst,
                                              int src_stride, int col_off) {
    int n0 = blockIdx.x * 64;
    int bh = blockIdx.y;
    int b = bh >> 4, h = bh & 15;
    __shared__ unsigned short t[64][65];
    int tx = threadIdx.x & 63, ty = threadIdx.x >> 6;  // 64 x 4
    const unsigned short* s = src + (size_t)(b * 2048 + n0) * src_stride + col_off + h * 64;
#pragma unroll
    for (int i = 0; i < 16; ++i) {
        int n = ty * 16 + i;
        t[n][tx] = s[(size_t)n * src_stride + tx];
    }
    __syncthreads();
    unsigned short* d = dst + (size_t)bh * 64 * 2048 + n0;
#pragma unroll
    for (int i = 0; i < 16; ++i) {
        int dd = ty * 16 + i;
        d[(size_t)dd * 2048 + tx] = t[tx][dd];
    }
}

// ---------------- flash attention, swapped-operand 32x32, no LDS ----------------
// Per wave: 32 q-rows. S^T = mfma32(K, Q^T): lane holds q=lane&31, k spread over
// 16 regs + lane>>5 half. O^T = mfma32(V^T, P^T): lane keeps its q, d in regs.
// K/V^T fragments read directly from global (L2-resident), 1-tile prefetch.
__global__ __launch_bounds__(256) void attn(const unsigned short* __restrict__ Q, int q_stride, int q_off,
                                            const unsigned short* __restrict__ Kp, int k_stride, int k_off,
                                            const unsigned short* __restrict__ Vt,
                                            const float* __restrict__ res,
                                            float* __restrict__ out) {
    const int qt = blockIdx.x;   // 0..15
    const int bh = blockIdx.y;   // 0..31
    const int b = bh >> 4, h = bh & 15;
    const int lane = threadIdx.x & 63, w = threadIdx.x >> 6;
    const int l31 = lane & 31, l5 = lane >> 5;

    const int q0 = qt * 128 + w * 32;

    // Q fragments (B-operand): col q = l31, k(d) = i*16 + l5*8 + j
    const unsigned short* qp = Q + (size_t)(b * 2048 + q0 + l31) * q_stride + q_off + h * 64 + l5 * 8;
    bf16x8 qf[4];
#pragma unroll
    for (int i = 0; i < 4; ++i) qf[i] = *(const bf16x8*)&qp[i * 16];

    // K fragment base (A-operand): row k = l31, d = i*16 + l5*8 + j
    const unsigned short* kbase = Kp + (size_t)(b * 2048 + l31) * k_stride + k_off + h * 64 + l5 * 8;
    // V^T fragment base (A-operand): row d = dh*32 + l31, k = n0 + c*16 + l5*8 + j
    const unsigned short* vbase = Vt + (size_t)bh * 64 * 2048 + (size_t)l31 * 2048 + l5 * 8;

    f32x16 oacc[2] = {};
    float m = -1e30f, l = 0.f;

    bf16x8 kf[4], vf[4];
#pragma unroll
    for (int i = 0; i < 4; ++i) kf[i] = *(const bf16x8*)&kbase[i * 16];
#pragma unroll
    for (int i = 0; i < 4; ++i)
        vf[i] = *(const bf16x8*)&vbase[(size_t)((i >> 1) * 32) * 2048 + (i & 1) * 16];

    for (int n0 = 0; n0 < 2048; n0 += 32) {
        // prefetch next tile's fragments (wraps to 0 on last iter; cheap, valid)
        const int nn = (n0 + 32 < 2048) ? (n0 + 32) : 0;
        bf16x8 kn[4], vn[4];
        {
            const unsigned short* kp = kbase + (size_t)nn * k_stride;
#pragma unroll
            for (int i = 0; i < 4; ++i) kn[i] = *(const bf16x8*)&kp[i * 16];
            const unsigned short* vp = vbase + nn;
#pragma unroll
            for (int i = 0; i < 4; ++i)
                vn[i] = *(const bf16x8*)&vp[(size_t)((i >> 1) * 32) * 2048 + (i & 1) * 16];
        }

        // S^T = K · Q^T  (lane: q = l31; k_local = (r&3) + 8*(r>>2) + 4*l5)
        f32x16 s = {};
#pragma unroll
        for (int i = 0; i < 4; ++i) s = mfma32(kf[i], qf[i], s);

        // online softmax, base-2, in-lane
        float mx = s[0];
#pragma unroll
        for (int r = 1; r < 16; ++r) mx = fmaxf(mx, s[r]);
        mx = fmaxf(mx, __shfl_xor(mx, 32));
        if (!__all(mx - m <= 8.f)) {  // defer-max (T13): P bounded by 2^8
            float mnew = fmaxf(m, mx);
            float al = __builtin_amdgcn_exp2f(m - mnew);
            m = mnew;
            l *= al;
#pragma unroll
            for (int dh = 0; dh < 2; ++dh)
#pragma unroll
                for (int r = 0; r < 16; ++r) oacc[dh][r] *= al;
        }
        float p[16];
        float ssum = 0.f;
#pragma unroll
        for (int r = 0; r < 16; ++r) { p[r] = __builtin_amdgcn_exp2f(s[r] - m); ssum += p[r]; }
        ssum += __shfl_xor(ssum, 32);
        l += ssum;

        // P^T -> B-operand fragments via cvt_pk + permlane32_swap (T12)
        bf16x8 pf[2];
#pragma unroll
        for (int c = 0; c < 2; ++c) {
            unsigned a0 = cvt_pk_bf16(p[8 * c + 0], p[8 * c + 1]);
            unsigned a1 = cvt_pk_bf16(p[8 * c + 4], p[8 * c + 5]);
            unsigned b0 = cvt_pk_bf16(p[8 * c + 2], p[8 * c + 3]);
            unsigned b1 = cvt_pk_bf16(p[8 * c + 6], p[8 * c + 7]);
            asm volatile("v_permlane32_swap_b32 %0, %1" : "+v"(a0), "+v"(a1));
            asm volatile("v_permlane32_swap_b32 %0, %1" : "+v"(b0), "+v"(b1));
            union { unsigned u[4]; bf16x8 v; } pu;
            pu.u[0] = a0; pu.u[1] = b0; pu.u[2] = a1; pu.u[3] = b1;
            pf[c] = pu.v;
        }

        // O^T += V^T · P^T
#pragma unroll
        for (int dh = 0; dh < 2; ++dh)
#pragma unroll
            for (int c = 0; c < 2; ++c)
                oacc[dh] = mfma32(vf[dh * 2 + c], pf[c], oacc[dh]);

#pragma unroll
        for (int i = 0; i < 4; ++i) { kf[i] = kn[i]; vf[i] = vn[i]; }
    }

    // epilogue: O/l + residual.  d_local = (reg&3) + 8*(reg>>2) + 4*l5
    const float inv = 1.0f / l;
    const size_t rowoff = (size_t)(b * 2048 + q0 + l31) * 1024 + h * 64;
#pragma unroll
    for (int dh = 0; dh < 2; ++dh) {
#pragma unroll
        for (int g = 0; g < 4; ++g) {
            const int col = dh * 32 + g * 8 + l5 * 4;
            f32x4 rv = *(const f32x4*)&res[rowoff + col];
            f32x4 ov;
#pragma unroll
            for (int r = 0; r < 4; ++r) ov[r] = oacc[dh][g * 4 + r] * inv + rv[r];
            *(f32x4*)&out[rowoff + col] = ov;
        }
    }
}

// ---------------- host ----------------
extern "C" void kernel_launch(void* const* d_in, const int* in_sizes, int n_in,
                              void* d_out, int out_size, void* d_ws, size_t ws_size,
                              hipStream_t stream) {
    const float* x      = (const float*)d_in[0];
    const float* feat   = (const float*)d_in[1];
    const float* norm_g = (const float*)d_in[2];
    const float* norm_b = (const float*)d_in[3];
    const float* W_cq   = (const float*)d_in[4];
    const float* W_ckv  = (const float*)d_in[5];
    const float* W_sqkv = (const float*)d_in[6];
    const float* ffn_g  = (const float*)d_in[7];
    const float* ffn_b  = (const float*)d_in[8];
    const float* W1     = (const float*)d_in[9];
    const float* b1     = (const float*)d_in[10];
    const float* W2     = (const float*)d_in[11];
    const float* b2     = (const float*)d_in[12];
    float* out = (float*)d_out;

    char* ws = (char*)d_ws;
    unsigned short* wq_t   = (unsigned short*)(ws + (size_t)(0u)   * (1u << 20));  // 2MB
    unsigned short* wkv_t  = (unsigned short*)(ws + (size_t)(2u)   * (1u << 20));  // 1.5MB
    unsigned short* wqkv_t = (unsigned short*)(ws + (size_t)(4u)   * (1u << 20));  // 6MB
    unsigned short* w1_t   = (unsigned short*)(ws + (size_t)(10u)  * (1u << 20));  // 8MB
    unsigned short* w2_t   = (unsigned short*)(ws + (size_t)(18u)  * (1u << 20));  // 8MB
    unsigned short* featb  = (unsigned short*)(ws + (size_t)(26u)  * (1u << 20));  // 3MB
    unsigned short* t0     = (unsigned short*)(ws + (size_t)(29u)  * (1u << 20));  // 8MB
    float*          cross  = (float*)        (ws + (size_t)(37u)  * (1u << 20));   // 16MB
    unsigned short* qb     = (unsigned short*)(ws + (size_t)(53u)  * (1u << 20));  // 8MB
    unsigned short* kvb    = (unsigned short*)(ws + (size_t)(61u)  * (1u << 20));  // 16MB
    unsigned short* qkvb   = (unsigned short*)(ws + (size_t)(77u)  * (1u << 20));  // 24MB
    unsigned short* vtb    = (unsigned short*)(ws + (size_t)(101u) * (1u << 20));  // 8MB
    unsigned short* h1     = (unsigned short*)(ws + (size_t)(53u)  * (1u << 20));  // 32MB (aliases q/kv/qkv, dead by FFN)

    // weights -> bf16 transposed [N,K]
    wconv_t<<<dim3(1024 / 32, 1024 / 32), 256, 0, stream>>>(W_cq,   wq_t,   1024, 1024);
    wconv_t<<<dim3(384 / 32,  2048 / 32), 256, 0, stream>>>(W_ckv,  wkv_t,  384,  2048);
    wconv_t<<<dim3(1024 / 32, 3072 / 32), 256, 0, stream>>>(W_sqkv, wqkv_t, 1024, 3072);
    wconv_t<<<dim3(1024 / 32, 4096 / 32), 256, 0, stream>>>(W1,     w1_t,   1024, 4096);
    wconv_t<<<dim3(4096 / 32, 1024 / 32), 256, 0, stream>>>(W2,     w2_t,   4096, 1024);
    fconv<<<dim3((4096 * 384 / 4) / 256), 256, 0, stream>>>(feat, featb, 4096 * 384 / 4);

    // ---- cross attention ----
    lnorm<<<4096, 256, 0, stream>>>(x, norm_g, norm_b, t0);
    gemm_bt<0, true ><<<dim3(32, 8),  256, 0, stream>>>(t0,    wq_t,  qb,  nullptr, nullptr, 4096, 1024, 1024, 1024);
    gemm_bt<0, false><<<dim3(32, 16), 256, 0, stream>>>(featb, wkv_t, kvb, nullptr, nullptr, 4096, 2048, 384,  0);
    vtrans<<<dim3(32, 32), 256, 0, stream>>>(kvb, vtb, 2048, 1024);
    attn<<<dim3(16, 32), 256, 0, stream>>>(qb, 1024, 0, kvb, 2048, 0, vtb, x, cross);

    // ---- self attention ----
    lnorm<<<4096, 256, 0, stream>>>(cross, norm_g, norm_b, t0);
    gemm_bt<0, true ><<<dim3(32, 24), 256, 0, stream>>>(t0, wqkv_t, qkvb, nullptr, nullptr, 4096, 3072, 1024, 1024);
    vtrans<<<dim3(32, 32), 256, 0, stream>>>(qkvb, vtb, 3072, 2048);
    attn<<<dim3(16, 32), 256, 0, stream>>>(qkvb, 3072, 0, qkvb, 3072, 1024, vtb, cross, out);

    // ---- FFN ----
    lnorm<<<4096, 256, 0, stream>>>(out, ffn_g, ffn_b, t0);
    gemm_bt<1, false><<<dim3(32, 32), 256, 0, stream>>>(t0, w1_t, h1, b1, nullptr, 4096, 4096, 1024, 0);
    gemm_bt<2, false><<<dim3(32, 8),  256, 0, stream>>>(h1, w2_t, out, b2, (const float*)out, 4096, 1024, 4096, 0);
}

// Round 3
// 421.189 us; speedup vs baseline: 1.2760x; 1.2758x over previous
//
#include <hip/hip_runtime.h>
#include <math.h>
#include <stdint.h>

typedef __attribute__((ext_vector_type(8)))  short   short8;
typedef __attribute__((ext_vector_type(4)))  short   short4v;
typedef __attribute__((ext_vector_type(8)))  __bf16  bf16x8;
typedef __attribute__((ext_vector_type(4)))  float   f32x4;
typedef __attribute__((ext_vector_type(16))) float   f32x16;

__device__ __forceinline__ unsigned short f2b(float f) {
    union { float f; unsigned u; } v; v.f = f;
    unsigned r = v.u + 0x7FFF + ((v.u >> 16) & 1);
    return (unsigned short)(r >> 16);
}

__device__ __forceinline__ f32x4 mfma_bf16(bf16x8 a, bf16x8 b, f32x4 c) {
    return __builtin_amdgcn_mfma_f32_16x16x32_bf16(a, b, c, 0, 0, 0);
}

__device__ __forceinline__ f32x16 mfma32(bf16x8 a, bf16x8 b, f32x16 c) {
    return __builtin_amdgcn_mfma_f32_32x32x16_bf16(a, b, c, 0, 0, 0);
}

__device__ __forceinline__ unsigned cvt_pk_bf16(float lo, float hi) {
    unsigned r;
    asm volatile("v_cvt_pk_bf16_f32 %0, %1, %2" : "=v"(r) : "v"(lo), "v"(hi));
    return r;
}

__device__ __forceinline__ void gload_lds16(const unsigned short* g, unsigned short* l) {
    __builtin_amdgcn_global_load_lds(
        (const __attribute__((address_space(1))) void*)g,
        (__attribute__((address_space(3))) void*)l,
        16, 0, 0);
}

// 0.125 (d_head^-0.5) * log2(e): softmax computed in base-2 (exact rescale)
#define QSCALE 0.18033688011112042592f

// ---------------- weight transpose + f32->bf16 ----------------
__global__ __launch_bounds__(256) void wconv_t(const float* __restrict__ W,
                                               unsigned short* __restrict__ Wt,
                                               int K, int N) {
    __shared__ float tile[32][33];
    int bk = blockIdx.x * 32;
    int bn = blockIdx.y * 32;
    int tx = threadIdx.x & 31, ty = threadIdx.x >> 5;  // 32 x 8
#pragma unroll
    for (int i = 0; i < 4; ++i) {
        int r = ty + i * 8;
        tile[r][tx] = W[(size_t)(bk + r) * N + bn + tx];
    }
    __syncthreads();
#pragma unroll
    for (int i = 0; i < 4; ++i) {
        int r = ty + i * 8;
        Wt[(size_t)(bn + r) * K + bk + tx] = f2b(tile[tx][r]);
    }
}

// ---------------- f32 -> bf16 elementwise (x4) ----------------
__global__ __launch_bounds__(256) void fconv(const float* __restrict__ in,
                                             unsigned short* __restrict__ out, int n4) {
    int i = blockIdx.x * 256 + threadIdx.x;
    if (i >= n4) return;
    f32x4 v = ((const f32x4*)in)[i];
    short4v o;
    o.x = (short)f2b(v.x); o.y = (short)f2b(v.y);
    o.z = (short)f2b(v.z); o.w = (short)f2b(v.w);
    ((short4v*)out)[i] = o;
}

// ---------------- layernorm (C=1024), f32 in -> bf16 out ----------------
__global__ __launch_bounds__(256) void lnorm(const float* __restrict__ x,
                                             const float* __restrict__ g,
                                             const float* __restrict__ bta,
                                             unsigned short* __restrict__ out) {
    int row = blockIdx.x;
    const f32x4* xr = (const f32x4*)(x + (size_t)row * 1024);
    int t = threadIdx.x;
    f32x4 v = xr[t];
    float s  = v.x + v.y + v.z + v.w;
    float s2 = v.x * v.x + v.y * v.y + v.z * v.z + v.w * v.w;
#pragma unroll
    for (int m = 1; m < 64; m <<= 1) {
        s  += __shfl_xor(s, m);
        s2 += __shfl_xor(s2, m);
    }
    __shared__ float rs[8];
    int w = t >> 6;
    if ((t & 63) == 0) { rs[w] = s; rs[4 + w] = s2; }
    __syncthreads();
    s  = rs[0] + rs[1] + rs[2] + rs[3];
    s2 = rs[4] + rs[5] + rs[6] + rs[7];
    float mean = s * (1.0f / 1024.0f);
    float var  = s2 * (1.0f / 1024.0f) - mean * mean;
    float rstd = rsqrtf(var + 1e-5f);
    f32x4 gv = ((const f32x4*)g)[t];
    f32x4 bv = ((const f32x4*)bta)[t];
    short4v o;
    o.x = (short)f2b((v.x - mean) * rstd * gv.x + bv.x);
    o.y = (short)f2b((v.y - mean) * rstd * gv.y + bv.y);
    o.z = (short)f2b((v.z - mean) * rstd * gv.z + bv.z);
    o.w = (short)f2b((v.w - mean) * rstd * gv.w + bv.w);
    ((short4v*)(out + (size_t)row * 1024))[t] = o;
}

// ---------------- GEMM: A[M,K] bf16 x Bt[N,K] bf16 -> C[M,N] ----------------
// EPI: 0 = bf16 out (optional q-scale on cols < scale_cols)
//      1 = bf16 out, +bias, exact GELU
//      2 = f32 out, +bias, +f32 residual
template <int EPI, bool SCALE_Q>
__global__ __launch_bounds__(256) void gemm_bt(const unsigned short* __restrict__ A,
                                               const unsigned short* __restrict__ Bt,
                                               void* __restrict__ C,
                                               const float* __restrict__ bias,
                                               const float* __restrict__ resid,
                                               int M, int N, int K, int scale_cols) {
    // bijective XCD swizzle (nwg % 8 == 0 for all our grids): m-major per XCD
    int flat = blockIdx.x + gridDim.x * blockIdx.y;
    const int qq = (gridDim.x * gridDim.y) >> 3;
    int wk = (flat & 7) * qq + (flat >> 3);
    const int m0 = (wk / (int)gridDim.y) * 128;
    const int n0 = (wk % (int)gridDim.y) * 128;

    __shared__ unsigned short As[128 * 64];
    __shared__ unsigned short Bs[128 * 64];
    const int tid  = threadIdx.x;
    const int lane = tid & 63;
    const int wid  = tid >> 6;
    const int wm = wid >> 1, wn = wid & 1;  // 2x2 waves, 64x64 each

    f32x4 acc[4][4] = {};

    const int srow = tid >> 3;        // 0..31
    const int scol = (tid & 7) * 8;   // element col

    for (int k0 = 0; k0 < K; k0 += 64) {
#pragma unroll
        for (int i = 0; i < 4; ++i)
            gload_lds16(A + (size_t)(m0 + srow + i * 32) * K + k0 + scol,
                        &As[(srow + i * 32) * 64 + scol]);
#pragma unroll
        for (int i = 0; i < 4; ++i)
            gload_lds16(Bt + (size_t)(n0 + srow + i * 32) * K + k0 + scol,
                        &Bs[(srow + i * 32) * 64 + scol]);
        __syncthreads();
#pragma unroll
        for (int kk = 0; kk < 2; ++kk) {
            const int ko = kk * 32 + (lane >> 4) * 8;
            bf16x8 a[4], b[4];
#pragma unroll
            for (int mi = 0; mi < 4; ++mi)
                a[mi] = *(const bf16x8*)&As[(wm * 64 + mi * 16 + (lane & 15)) * 64 + ko];
#pragma unroll
            for (int ni = 0; ni < 4; ++ni)
                b[ni] = *(const bf16x8*)&Bs[(wn * 64 + ni * 16 + (lane & 15)) * 64 + ko];
#pragma unroll
            for (int mi = 0; mi < 4; ++mi)
#pragma unroll
                for (int ni = 0; ni < 4; ++ni)
                    acc[mi][ni] = mfma_bf16(a[mi], b[ni], acc[mi][ni]);
        }
        __syncthreads();
    }

    const int rbase = m0 + wm * 64 + (lane >> 4) * 4;
    const int cbase = n0 + wn * 64 + (lane & 15);
#pragma unroll
    for (int mi = 0; mi < 4; ++mi) {
#pragma unroll
        for (int r = 0; r < 4; ++r) {
            const int row = rbase + mi * 16 + r;
#pragma unroll
            for (int ni = 0; ni < 4; ++ni) {
                const int col = cbase + ni * 16;
                float v = acc[mi][ni][r];
                if (EPI == 0) {
                    if (SCALE_Q && col < scale_cols) v *= QSCALE;
                    ((unsigned short*)C)[(size_t)row * N + col] = f2b(v);
                } else if (EPI == 1) {
                    v += bias[col];
                    v = 0.5f * v * (1.0f + erff(v * 0.70710678118f));
                    ((unsigned short*)C)[(size_t)row * N + col] = f2b(v);
                } else {
                    v += bias[col] + resid[(size_t)row * N + col];
                    ((float*)C)[(size_t)row * N + col] = v;
                }
            }
        }
    }
}

// ---------------- V transpose: [b,n, col_off + h*64 + d] -> Vt[bh][d][n] ----------------
__global__ __launch_bounds__(256) void vtrans(const unsigned short* __restrict__ src,
                                              unsigned short* __restrict__ dst,
                                              int src_stride, int col_off) {
    int n0 = blockIdx.x * 64;
    int bh = blockIdx.y;
    int b = bh >> 4, h = bh & 15;
    __shared__ unsigned short t[64][65];
    int tx = threadIdx.x & 63, ty = threadIdx.x >> 6;  // 64 x 4
    const unsigned short* s = src + (size_t)(b * 2048 + n0) * src_stride + col_off + h * 64;
#pragma unroll
    for (int i = 0; i < 16; ++i) {
        int n = ty * 16 + i;
        t[n][tx] = s[(size_t)n * src_stride + tx];
    }
    __syncthreads();
    unsigned short* d = dst + (size_t)bh * 64 * 2048 + n0;
#pragma unroll
    for (int i = 0; i < 16; ++i) {
        int dd = ty * 16 + i;
        d[(size_t)dd * 2048 + tx] = t[tx][dd];
    }
}

// ---------------- flash attention, swapped-operand 32x32, LDS-staged K/V ----------------
// Per wave: 32 q-rows. S^T = mfma32(K, Q^T): lane holds q=lane&31, k in regs.
// O^T = mfma32(V^T, P^T): lane keeps its q, d in regs (rescale is lane-local).
// K [64k][64d] and V^T [64d][64n] tiles double-buffered in LDS via global_load_lds,
// XOR-swizzled on the GLOBAL SOURCE column (write side) and on the ds_read address
// (read side) — same involution, rule #21. XCD-clustered bh for L2-resident K/V.
__global__ __launch_bounds__(256) void attn(const unsigned short* __restrict__ Q, int q_stride, int q_off,
                                            const unsigned short* __restrict__ Kp, int k_stride, int k_off,
                                            const unsigned short* __restrict__ Vt,
                                            const float* __restrict__ res,
                                            float* __restrict__ out) {
    // 512 blocks; XCD = bid%8 gets 4 bh values -> K/V (2MB) L2-resident per XCD
    const int bid = blockIdx.x;
    const int slot = bid >> 3;
    const int bh = (bid & 7) * 4 + (slot >> 4);
    const int qt = slot & 15;
    const int b = bh >> 4, h = bh & 15;
    const int lane = threadIdx.x & 63, w = threadIdx.x >> 6;
    const int l31 = lane & 31, l5 = lane >> 5;

    __shared__ unsigned short Ks[2][64 * 64];
    __shared__ unsigned short Vs[2][64 * 64];

    const int q0 = qt * 128 + w * 32;

    // Q fragments (B-operand): col q = l31, d = i*16 + l5*8 + j
    const unsigned short* qp = Q + (size_t)(b * 2048 + q0 + l31) * q_stride + q_off + h * 64 + l5 * 8;
    bf16x8 qf[4];
#pragma unroll
    for (int i = 0; i < 4; ++i) qf[i] = *(const bf16x8*)&qp[i * 16];

    const unsigned short* kg = Kp + (size_t)(b * 2048) * k_stride + k_off + h * 64;
    const unsigned short* vg = Vt + (size_t)bh * 64 * 2048;

    // staging: wave w covers rows w*16..w*16+16 (2 instrs of 8 rows); source col
    // pre-swizzled so LDS stays linear per-instruction.
    const int sgrow = lane >> 3;                          // row within 8-row group
    const int sgcol = (((lane & 7) ^ sgrow) << 3);        // element col (16B granule XOR)

    f32x16 oacc[2] = {};
    float m = -1e30f, l = 0.f;

    const int kxor = (l31 & 7) << 3;   // read-side XOR (elements)

    // ---- prologue: stage tile 0 ----
#pragma unroll
    for (int t8 = 0; t8 < 2; ++t8) {
        const int rb = w * 16 + t8 * 8;
        gload_lds16(kg + (size_t)(rb + sgrow) * k_stride + sgcol, &Ks[0][rb * 64]);
        gload_lds16(vg + (size_t)(rb + sgrow) * 2048 + sgcol,     &Vs[0][rb * 64]);
    }
    __syncthreads();

    for (int t = 0; t < 32; ++t) {
        const int cur = t & 1;
        // stage next tile into the other buffer (overlaps with compute below)
        if (t + 1 < 32) {
            const int n1 = (t + 1) * 64;
#pragma unroll
            for (int t8 = 0; t8 < 2; ++t8) {
                const int rb = w * 16 + t8 * 8;
                gload_lds16(kg + (size_t)(n1 + rb + sgrow) * k_stride + sgcol, &Ks[cur ^ 1][rb * 64]);
                gload_lds16(vg + (size_t)(rb + sgrow) * 2048 + n1 + sgcol,     &Vs[cur ^ 1][rb * 64]);
            }
        }

        // K fragments (A-operand): row k = ks*32 + l31, d = i*16 + l5*8 + j
        bf16x8 kf[2][4];
#pragma unroll
        for (int ks = 0; ks < 2; ++ks)
#pragma unroll
            for (int i = 0; i < 4; ++i)
                kf[ks][i] = *(const bf16x8*)&Ks[cur][(ks * 32 + l31) * 64 + ((i * 16 + l5 * 8) ^ kxor)];

        f32x16 s0 = {}, s1 = {};
#pragma unroll
        for (int i = 0; i < 4; ++i) s0 = mfma32(kf[0][i], qf[i], s0);
#pragma unroll
        for (int i = 0; i < 4; ++i) s1 = mfma32(kf[1][i], qf[i], s1);

        // V fragments (A-operand): row d = dh*32 + l31, k = c*16 + l5*8 + j
        bf16x8 vf[2][4];
#pragma unroll
        for (int dh = 0; dh < 2; ++dh)
#pragma unroll
            for (int c = 0; c < 4; ++c)
                vf[dh][c] = *(const bf16x8*)&Vs[cur][(dh * 32 + l31) * 64 + ((c * 16 + l5 * 8) ^ kxor)];

        // online softmax (base-2, q lane-local)
        float mx = s0[0];
#pragma unroll
        for (int r = 1; r < 16; ++r) mx = fmaxf(mx, s0[r]);
#pragma unroll
        for (int r = 0; r < 16; ++r) mx = fmaxf(mx, s1[r]);
        mx = fmaxf(mx, __shfl_xor(mx, 32));
        if (!__all(mx - m <= 8.f)) {  // defer-max (T13)
            float mnew = fmaxf(m, mx);
            float al = __builtin_amdgcn_exp2f(m - mnew);
            m = mnew;
            l *= al;
#pragma unroll
            for (int dh = 0; dh < 2; ++dh)
#pragma unroll
                for (int r = 0; r < 16; ++r) oacc[dh][r] *= al;
        }
        float p0[16], p1[16];
        float ssum = 0.f;
#pragma unroll
        for (int r = 0; r < 16; ++r) { p0[r] = __builtin_amdgcn_exp2f(s0[r] - m); ssum += p0[r]; }
#pragma unroll
        for (int r = 0; r < 16; ++r) { p1[r] = __builtin_amdgcn_exp2f(s1[r] - m); ssum += p1[r]; }
        ssum += __shfl_xor(ssum, 32);
        l += ssum;

        // P^T -> B-operand fragments via cvt_pk + permlane32_swap (T12)
        bf16x8 pf[4];
#pragma unroll
        for (int half = 0; half < 2; ++half) {
            const float* p = half ? p1 : p0;
#pragma unroll
            for (int c = 0; c < 2; ++c) {
                unsigned a0 = cvt_pk_bf16(p[8 * c + 0], p[8 * c + 1]);
                unsigned a1 = cvt_pk_bf16(p[8 * c + 4], p[8 * c + 5]);
                unsigned b0 = cvt_pk_bf16(p[8 * c + 2], p[8 * c + 3]);
                unsigned b1 = cvt_pk_bf16(p[8 * c + 6], p[8 * c + 7]);
                asm volatile("v_permlane32_swap_b32 %0, %1" : "+v"(a0), "+v"(a1));
                asm volatile("v_permlane32_swap_b32 %0, %1" : "+v"(b0), "+v"(b1));
                union { unsigned u[4]; bf16x8 v; } pu;
                pu.u[0] = a0; pu.u[1] = b0; pu.u[2] = a1; pu.u[3] = b1;
                pf[half * 2 + c] = pu.v;
            }
        }

        // O^T += V^T · P^T
#pragma unroll
        for (int dh = 0; dh < 2; ++dh)
#pragma unroll
            for (int c = 0; c < 4; ++c)
                oacc[dh] = mfma32(vf[dh][c], pf[c], oacc[dh]);

        __syncthreads();  // drains stage DMA (vmcnt) + protects buffer reuse
    }

    // epilogue: O/l + residual.  d_local = (reg&3) + 8*(reg>>2) + 4*l5
    const float inv = 1.0f / l;
    const size_t rowoff = (size_t)(b * 2048 + q0 + l31) * 1024 + h * 64;
#pragma unroll
    for (int dh = 0; dh < 2; ++dh) {
#pragma unroll
        for (int g = 0; g < 4; ++g) {
            const int col = dh * 32 + g * 8 + l5 * 4;
            f32x4 rv = *(const f32x4*)&res[rowoff + col];
            f32x4 ov;
#pragma unroll
            for (int r = 0; r < 4; ++r) ov[r] = oacc[dh][g * 4 + r] * inv + rv[r];
            *(f32x4*)&out[rowoff + col] = ov;
        }
    }
}

// ---------------- host ----------------
extern "C" void kernel_launch(void* const* d_in, const int* in_sizes, int n_in,
                              void* d_out, int out_size, void* d_ws, size_t ws_size,
                              hipStream_t stream) {
    const float* x      = (const float*)d_in[0];
    const float* feat   = (const float*)d_in[1];
    const float* norm_g = (const float*)d_in[2];
    const float* norm_b = (const float*)d_in[3];
    const float* W_cq   = (const float*)d_in[4];
    const float* W_ckv  = (const float*)d_in[5];
    const float* W_sqkv = (const float*)d_in[6];
    const float* ffn_g  = (const float*)d_in[7];
    const float* ffn_b  = (const float*)d_in[8];
    const float* W1     = (const float*)d_in[9];
    const float* b1     = (const float*)d_in[10];
    const float* W2     = (const float*)d_in[11];
    const float* b2     = (const float*)d_in[12];
    float* out = (float*)d_out;

    char* ws = (char*)d_ws;
    unsigned short* wq_t   = (unsigned short*)(ws + (size_t)(0u)   * (1u << 20));  // 2MB
    unsigned short* wkv_t  = (unsigned short*)(ws + (size_t)(2u)   * (1u << 20));  // 1.5MB
    unsigned short* wqkv_t = (unsigned short*)(ws + (size_t)(4u)   * (1u << 20));  // 6MB
    unsigned short* w1_t   = (unsigned short*)(ws + (size_t)(10u)  * (1u << 20));  // 8MB
    unsigned short* w2_t   = (unsigned short*)(ws + (size_t)(18u)  * (1u << 20));  // 8MB
    unsigned short* featb  = (unsigned short*)(ws + (size_t)(26u)  * (1u << 20));  // 3MB
    unsigned short* t0     = (unsigned short*)(ws + (size_t)(29u)  * (1u << 20));  // 8MB
    float*          cross  = (float*)        (ws + (size_t)(37u)  * (1u << 20));   // 16MB
    unsigned short* qb     = (unsigned short*)(ws + (size_t)(53u)  * (1u << 20));  // 8MB
    unsigned short* kvb    = (unsigned short*)(ws + (size_t)(61u)  * (1u << 20));  // 16MB
    unsigned short* qkvb   = (unsigned short*)(ws + (size_t)(77u)  * (1u << 20));  // 24MB
    unsigned short* vtb    = (unsigned short*)(ws + (size_t)(101u) * (1u << 20));  // 8MB
    unsigned short* h1     = (unsigned short*)(ws + (size_t)(53u)  * (1u << 20));  // 32MB (aliases q/kv/qkv, dead by FFN)

    // weights -> bf16 transposed [N,K]
    wconv_t<<<dim3(1024 / 32, 1024 / 32), 256, 0, stream>>>(W_cq,   wq_t,   1024, 1024);
    wconv_t<<<dim3(384 / 32,  2048 / 32), 256, 0, stream>>>(W_ckv,  wkv_t,  384,  2048);
    wconv_t<<<dim3(1024 / 32, 3072 / 32), 256, 0, stream>>>(W_sqkv, wqkv_t, 1024, 3072);
    wconv_t<<<dim3(1024 / 32, 4096 / 32), 256, 0, stream>>>(W1,     w1_t,   1024, 4096);
    wconv_t<<<dim3(4096 / 32, 1024 / 32), 256, 0, stream>>>(W2,     w2_t,   4096, 1024);
    fconv<<<dim3((4096 * 384 / 4) / 256), 256, 0, stream>>>(feat, featb, 4096 * 384 / 4);

    // ---- cross attention ----
    lnorm<<<4096, 256, 0, stream>>>(x, norm_g, norm_b, t0);
    gemm_bt<0, true ><<<dim3(32, 8),  256, 0, stream>>>(t0,    wq_t,  qb,  nullptr, nullptr, 4096, 1024, 1024, 1024);
    gemm_bt<0, false><<<dim3(32, 16), 256, 0, stream>>>(featb, wkv_t, kvb, nullptr, nullptr, 4096, 2048, 384,  0);
    vtrans<<<dim3(32, 32), 256, 0, stream>>>(kvb, vtb, 2048, 1024);
    attn<<<512, 256, 0, stream>>>(qb, 1024, 0, kvb, 2048, 0, vtb, x, cross);

    // ---- self attention ----
    lnorm<<<4096, 256, 0, stream>>>(cross, norm_g, norm_b, t0);
    gemm_bt<0, true ><<<dim3(32, 24), 256, 0, stream>>>(t0, wqkv_t, qkvb, nullptr, nullptr, 4096, 3072, 1024, 1024);
    vtrans<<<dim3(32, 32), 256, 0, stream>>>(qkvb, vtb, 3072, 2048);
    attn<<<512, 256, 0, stream>>>(qkvb, 3072, 0, qkvb, 3072, 1024, vtb, cross, out);

    // ---- FFN ----
    lnorm<<<4096, 256, 0, stream>>>(out, ffn_g, ffn_b, t0);
    gemm_bt<1, false><<<dim3(32, 32), 256, 0, stream>>>(t0, w1_t, h1, b1, nullptr, 4096, 4096, 1024, 0);
    gemm_bt<2, false><<<dim3(32, 8),  256, 0, stream>>>(h1, w2_t, out, b2, (const float*)out, 4096, 1024, 4096, 0);
}

// Round 4
// 365.399 us; speedup vs baseline: 1.4709x; 1.1527x over previous
//
#include <hip/hip_runtime.h>
#include <math.h>
#include <stdint.h>

typedef __attribute__((ext_vector_type(8)))  short   short8;
typedef __attribute__((ext_vector_type(4)))  short   short4v;
typedef __attribute__((ext_vector_type(8)))  __bf16  bf16x8;
typedef __attribute__((ext_vector_type(4)))  float   f32x4;
typedef __attribute__((ext_vector_type(16))) float   f32x16;

__device__ __forceinline__ unsigned short f2b(float f) {
    union { float f; unsigned u; } v; v.f = f;
    unsigned r = v.u + 0x7FFF + ((v.u >> 16) & 1);
    return (unsigned short)(r >> 16);
}

__device__ __forceinline__ f32x4 mfma_bf16(bf16x8 a, bf16x8 b, f32x4 c) {
    return __builtin_amdgcn_mfma_f32_16x16x32_bf16(a, b, c, 0, 0, 0);
}

__device__ __forceinline__ f32x16 mfma32(bf16x8 a, bf16x8 b, f32x16 c) {
    return __builtin_amdgcn_mfma_f32_32x32x16_bf16(a, b, c, 0, 0, 0);
}

__device__ __forceinline__ unsigned cvt_pk_bf16(float lo, float hi) {
    unsigned r;
    asm volatile("v_cvt_pk_bf16_f32 %0, %1, %2" : "=v"(r) : "v"(lo), "v"(hi));
    return r;
}

__device__ __forceinline__ void gload_lds16(const unsigned short* g, unsigned short* l) {
    __builtin_amdgcn_global_load_lds(
        (const __attribute__((address_space(1))) void*)g,
        (__attribute__((address_space(3))) void*)l,
        16, 0, 0);
}

// 0.125 (d_head^-0.5) * log2(e): softmax computed in base-2 (exact rescale)
#define QSCALE 0.18033688011112042592f

// ---------------- weight transpose + f32->bf16 ----------------
__global__ __launch_bounds__(256) void wconv_t(const float* __restrict__ W,
                                               unsigned short* __restrict__ Wt,
                                               int K, int N) {
    __shared__ float tile[32][33];
    int bk = blockIdx.x * 32;
    int bn = blockIdx.y * 32;
    int tx = threadIdx.x & 31, ty = threadIdx.x >> 5;  // 32 x 8
#pragma unroll
    for (int i = 0; i < 4; ++i) {
        int r = ty + i * 8;
        tile[r][tx] = W[(size_t)(bk + r) * N + bn + tx];
    }
    __syncthreads();
#pragma unroll
    for (int i = 0; i < 4; ++i) {
        int r = ty + i * 8;
        Wt[(size_t)(bn + r) * K + bk + tx] = f2b(tile[tx][r]);
    }
}

// ---------------- f32 -> bf16 elementwise (x4) ----------------
__global__ __launch_bounds__(256) void fconv(const float* __restrict__ in,
                                             unsigned short* __restrict__ out, int n4) {
    int i = blockIdx.x * 256 + threadIdx.x;
    if (i >= n4) return;
    f32x4 v = ((const f32x4*)in)[i];
    short4v o;
    o.x = (short)f2b(v.x); o.y = (short)f2b(v.y);
    o.z = (short)f2b(v.z); o.w = (short)f2b(v.w);
    ((short4v*)out)[i] = o;
}

// ---------------- layernorm (C=1024), f32 in -> bf16 out ----------------
__global__ __launch_bounds__(256) void lnorm(const float* __restrict__ x,
                                             const float* __restrict__ g,
                                             const float* __restrict__ bta,
                                             unsigned short* __restrict__ out) {
    int row = blockIdx.x;
    const f32x4* xr = (const f32x4*)(x + (size_t)row * 1024);
    int t = threadIdx.x;
    f32x4 v = xr[t];
    float s  = v.x + v.y + v.z + v.w;
    float s2 = v.x * v.x + v.y * v.y + v.z * v.z + v.w * v.w;
#pragma unroll
    for (int m = 1; m < 64; m <<= 1) {
        s  += __shfl_xor(s, m);
        s2 += __shfl_xor(s2, m);
    }
    __shared__ float rs[8];
    int w = t >> 6;
    if ((t & 63) == 0) { rs[w] = s; rs[4 + w] = s2; }
    __syncthreads();
    s  = rs[0] + rs[1] + rs[2] + rs[3];
    s2 = rs[4] + rs[5] + rs[6] + rs[7];
    float mean = s * (1.0f / 1024.0f);
    float var  = s2 * (1.0f / 1024.0f) - mean * mean;
    float rstd = rsqrtf(var + 1e-5f);
    f32x4 gv = ((const f32x4*)g)[t];
    f32x4 bv = ((const f32x4*)bta)[t];
    short4v o;
    o.x = (short)f2b((v.x - mean) * rstd * gv.x + bv.x);
    o.y = (short)f2b((v.y - mean) * rstd * gv.y + bv.y);
    o.z = (short)f2b((v.z - mean) * rstd * gv.z + bv.z);
    o.w = (short)f2b((v.w - mean) * rstd * gv.w + bv.w);
    ((short4v*)(out + (size_t)row * 1024))[t] = o;
}

// ---------------- pipelined GEMM: A[M,K] x Bt[N,K] -> C[M,N], BK=64 ----------------
// Counted-vmcnt double-buffer (T3/T4 depth-1): STAGE(next) -> vmcnt(8) -> barrier ->
// {ds_read + MFMA} x2 khalf -> barrier. T2 swizzle: source granule ^ (row&7) on
// stage, same XOR on ds_read (involution). setprio around MFMA clusters (T5).
// WM x WN waves, per-wave MI*16 rows x NI*16 cols.
// EPI: 0 = bf16 out (+QSCALE on cols < scale_cols if SCQ)
//      1 = bf16 out, +bias, exact GELU
//      2 = f32 out, +bias, +f32 residual
template <int WM, int WN, int MI, int NI, int EPI, bool SCQ>
__global__ __launch_bounds__(WM * WN * 64, 2)
void gemm8(const unsigned short* __restrict__ A,
           const unsigned short* __restrict__ Bt,
           void* __restrict__ C,
           const float* __restrict__ bias,
           const float* __restrict__ resid,
           int M, int N, int K, int scale_cols) {
    constexpr int BM = WM * MI * 16;
    constexpr int BN = WN * NI * 16;
    constexpr int THREADS = WM * WN * 64;
    constexpr int ROWS = THREADS / 8;          // rows per stage instr
    constexpr int IA = BM / ROWS;              // stage instrs for A
    constexpr int IB = BN / ROWS;

    // bijective XCD swizzle (all grids are multiples of 8), m-major per XCD
    const int nwg = gridDim.x;
    const int nby = N / BN;
    int flat = blockIdx.x;
    int wk = (flat & 7) * (nwg >> 3) + (flat >> 3);
    const int m0 = (wk / nby) * BM;
    const int n0 = (wk % nby) * BN;

    __shared__ unsigned short As[2][BM * 64];
    __shared__ unsigned short Bs[2][BN * 64];

    const int tid  = threadIdx.x;
    const int lane = tid & 63;
    const int wid  = tid >> 6;
    const int wm = wid / WN, wn = wid % WN;
    const int l15 = lane & 15, q4 = lane >> 4, xw = lane & 7;

    const int sr = tid >> 3;                    // stage row within group
    const int sg = (tid & 7) ^ (sr & 7);        // swizzled source granule

    const unsigned short* ag = A  + (size_t)(m0 + sr) * K + sg * 8;
    const unsigned short* bg = Bt + (size_t)(n0 + sr) * K + sg * 8;

    f32x4 acc[MI][NI] = {};

    auto STAGE = [&](int d, int t) {
        const int k0 = t * 64;
#pragma unroll
        for (int i = 0; i < IA; ++i)
            gload_lds16(ag + (size_t)(i * ROWS) * K + k0, &As[d][i * ROWS * 64 + tid * 8]);
#pragma unroll
        for (int i = 0; i < IB; ++i)
            gload_lds16(bg + (size_t)(i * ROWS) * K + k0, &Bs[d][i * ROWS * 64 + tid * 8]);
    };

    const int NT = K >> 6;
    STAGE(0, 0);

    for (int t = 0; t < NT; ++t) {
        const int c = t & 1;
        if (t + 1 < NT) STAGE(c ^ 1, t + 1);
        __builtin_amdgcn_sched_barrier(0);
        if (t + 1 < NT) asm volatile("s_waitcnt vmcnt(8)" ::: "memory");
        else            asm volatile("s_waitcnt vmcnt(0)" ::: "memory");
        __builtin_amdgcn_s_barrier();
        __builtin_amdgcn_sched_barrier(0);
#pragma unroll
        for (int h = 0; h < 2; ++h) {
            bf16x8 a[MI], b[NI];
            const int gsl = h * 4 + q4;         // granule before swizzle
#pragma unroll
            for (int mi = 0; mi < MI; ++mi)
                a[mi] = *(const bf16x8*)&As[c][(wm * MI * 16 + mi * 16 + l15) * 64 + ((gsl ^ xw) << 3)];
#pragma unroll
            for (int ni = 0; ni < NI; ++ni)
                b[ni] = *(const bf16x8*)&Bs[c][(wn * NI * 16 + ni * 16 + l15) * 64 + ((gsl ^ xw) << 3)];
            __builtin_amdgcn_s_setprio(1);
#pragma unroll
            for (int mi = 0; mi < MI; ++mi)
#pragma unroll
                for (int ni = 0; ni < NI; ++ni)
                    acc[mi][ni] = mfma_bf16(a[mi], b[ni], acc[mi][ni]);
            __builtin_amdgcn_s_setprio(0);
        }
        __builtin_amdgcn_sched_barrier(0);
        __builtin_amdgcn_s_barrier();
    }

    // epilogue
    const int rb = m0 + wm * MI * 16 + q4 * 4;
    const int cb = n0 + wn * NI * 16 + l15;
    float bv[NI];
    if (EPI >= 1) {
#pragma unroll
        for (int ni = 0; ni < NI; ++ni) bv[ni] = bias[cb + ni * 16];
    }
#pragma unroll
    for (int mi = 0; mi < MI; ++mi) {
#pragma unroll
        for (int r = 0; r < 4; ++r) {
            const int row = rb + mi * 16 + r;
#pragma unroll
            for (int ni = 0; ni < NI; ++ni) {
                const int col = cb + ni * 16;
                float v = acc[mi][ni][r];
                if (EPI == 0) {
                    if (SCQ && col < scale_cols) v *= QSCALE;
                    ((unsigned short*)C)[(size_t)row * N + col] = f2b(v);
                } else if (EPI == 1) {
                    v += bv[ni];
                    v = 0.5f * v * (1.0f + erff(v * 0.70710678118f));
                    ((unsigned short*)C)[(size_t)row * N + col] = f2b(v);
                } else {
                    v += bv[ni] + resid[(size_t)row * N + col];
                    ((float*)C)[(size_t)row * N + col] = v;
                }
            }
        }
    }
}

// ---------------- V transpose: [b,n, col_off + h*64 + d] -> Vt[bh][d][n] ----------------
__global__ __launch_bounds__(256) void vtrans(const unsigned short* __restrict__ src,
                                              unsigned short* __restrict__ dst,
                                              int src_stride, int col_off) {
    int n0 = blockIdx.x * 64;
    int bh = blockIdx.y;
    int b = bh >> 4, h = bh & 15;
    __shared__ unsigned short t[64][65];
    int tx = threadIdx.x & 63, ty = threadIdx.x >> 6;  // 64 x 4
    const unsigned short* s = src + (size_t)(b * 2048 + n0) * src_stride + col_off + h * 64;
#pragma unroll
    for (int i = 0; i < 16; ++i) {
        int n = ty * 16 + i;
        t[n][tx] = s[(size_t)n * src_stride + tx];
    }
    __syncthreads();
    unsigned short* d = dst + (size_t)bh * 64 * 2048 + n0;
#pragma unroll
    for (int i = 0; i < 16; ++i) {
        int dd = ty * 16 + i;
        d[(size_t)dd * 2048 + tx] = t[tx][dd];
    }
}

// ---------------- flash attention, swapped-operand 32x32, LDS-staged K/V ----------------
__global__ __launch_bounds__(256) void attn(const unsigned short* __restrict__ Q, int q_stride, int q_off,
                                            const unsigned short* __restrict__ Kp, int k_stride, int k_off,
                                            const unsigned short* __restrict__ Vt,
                                            const float* __restrict__ res,
                                            float* __restrict__ out) {
    // 512 blocks; XCD = bid%8 gets 4 bh values -> K/V (2MB) L2-resident per XCD
    const int bid = blockIdx.x;
    const int slot = bid >> 3;
    const int bh = (bid & 7) * 4 + (slot >> 4);
    const int qt = slot & 15;
    const int b = bh >> 4, h = bh & 15;
    const int lane = threadIdx.x & 63, w = threadIdx.x >> 6;
    const int l31 = lane & 31, l5 = lane >> 5;

    __shared__ unsigned short Ks[2][64 * 64];
    __shared__ unsigned short Vs[2][64 * 64];

    const int q0 = qt * 128 + w * 32;

    // Q fragments (B-operand): col q = l31, d = i*16 + l5*8 + j
    const unsigned short* qp = Q + (size_t)(b * 2048 + q0 + l31) * q_stride + q_off + h * 64 + l5 * 8;
    bf16x8 qf[4];
#pragma unroll
    for (int i = 0; i < 4; ++i) qf[i] = *(const bf16x8*)&qp[i * 16];

    const unsigned short* kg = Kp + (size_t)(b * 2048) * k_stride + k_off + h * 64;
    const unsigned short* vg = Vt + (size_t)bh * 64 * 2048;

    const int sgrow = lane >> 3;                          // row within 8-row group
    const int sgcol = (((lane & 7) ^ sgrow) << 3);        // element col (16B granule XOR)

    f32x16 oacc[2] = {};
    float m = -1e30f, l = 0.f;

    const int kxor = (l31 & 7) << 3;   // read-side XOR (elements)

    // ---- prologue: stage tile 0 ----
#pragma unroll
    for (int t8 = 0; t8 < 2; ++t8) {
        const int rb = w * 16 + t8 * 8;
        gload_lds16(kg + (size_t)(rb + sgrow) * k_stride + sgcol, &Ks[0][rb * 64]);
        gload_lds16(vg + (size_t)(rb + sgrow) * 2048 + sgcol,     &Vs[0][rb * 64]);
    }
    __syncthreads();

    for (int t = 0; t < 32; ++t) {
        const int cur = t & 1;
        if (t + 1 < 32) {
            const int n1 = (t + 1) * 64;
#pragma unroll
            for (int t8 = 0; t8 < 2; ++t8) {
                const int rb = w * 16 + t8 * 8;
                gload_lds16(kg + (size_t)(n1 + rb + sgrow) * k_stride + sgcol, &Ks[cur ^ 1][rb * 64]);
                gload_lds16(vg + (size_t)(rb + sgrow) * 2048 + n1 + sgcol,     &Vs[cur ^ 1][rb * 64]);
            }
        }

        // K fragments (A-operand): row k = ks*32 + l31, d = i*16 + l5*8 + j
        bf16x8 kf[2][4];
#pragma unroll
        for (int ks = 0; ks < 2; ++ks)
#pragma unroll
            for (int i = 0; i < 4; ++i)
                kf[ks][i] = *(const bf16x8*)&Ks[cur][(ks * 32 + l31) * 64 + ((i * 16 + l5 * 8) ^ kxor)];

        f32x16 s0 = {}, s1 = {};
#pragma unroll
        for (int i = 0; i < 4; ++i) s0 = mfma32(kf[0][i], qf[i], s0);
#pragma unroll
        for (int i = 0; i < 4; ++i) s1 = mfma32(kf[1][i], qf[i], s1);

        // V fragments (A-operand): row d = dh*32 + l31, k = c*16 + l5*8 + j
        bf16x8 vf[2][4];
#pragma unroll
        for (int dh = 0; dh < 2; ++dh)
#pragma unroll
            for (int c = 0; c < 4; ++c)
                vf[dh][c] = *(const bf16x8*)&Vs[cur][(dh * 32 + l31) * 64 + ((c * 16 + l5 * 8) ^ kxor)];

        // online softmax (base-2, q lane-local)
        float mx = s0[0];
#pragma unroll
        for (int r = 1; r < 16; ++r) mx = fmaxf(mx, s0[r]);
#pragma unroll
        for (int r = 0; r < 16; ++r) mx = fmaxf(mx, s1[r]);
        mx = fmaxf(mx, __shfl_xor(mx, 32));
        if (!__all(mx - m <= 8.f)) {  // defer-max (T13)
            float mnew = fmaxf(m, mx);
            float al = __builtin_amdgcn_exp2f(m - mnew);
            m = mnew;
            l *= al;
#pragma unroll
            for (int dh = 0; dh < 2; ++dh)
#pragma unroll
                for (int r = 0; r < 16; ++r) oacc[dh][r] *= al;
        }
        float p0[16], p1[16];
        float ssum = 0.f;
#pragma unroll
        for (int r = 0; r < 16; ++r) { p0[r] = __builtin_amdgcn_exp2f(s0[r] - m); ssum += p0[r]; }
#pragma unroll
        for (int r = 0; r < 16; ++r) { p1[r] = __builtin_amdgcn_exp2f(s1[r] - m); ssum += p1[r]; }
        ssum += __shfl_xor(ssum, 32);
        l += ssum;

        // P^T -> B-operand fragments via cvt_pk + permlane32_swap (T12)
        bf16x8 pf[4];
#pragma unroll
        for (int half = 0; half < 2; ++half) {
            const float* p = half ? p1 : p0;
#pragma unroll
            for (int c = 0; c < 2; ++c) {
                unsigned a0 = cvt_pk_bf16(p[8 * c + 0], p[8 * c + 1]);
                unsigned a1 = cvt_pk_bf16(p[8 * c + 4], p[8 * c + 5]);
                unsigned b0 = cvt_pk_bf16(p[8 * c + 2], p[8 * c + 3]);
                unsigned b1 = cvt_pk_bf16(p[8 * c + 6], p[8 * c + 7]);
                asm volatile("v_permlane32_swap_b32 %0, %1" : "+v"(a0), "+v"(a1));
                asm volatile("v_permlane32_swap_b32 %0, %1" : "+v"(b0), "+v"(b1));
                union { unsigned u[4]; bf16x8 v; } pu;
                pu.u[0] = a0; pu.u[1] = b0; pu.u[2] = a1; pu.u[3] = b1;
                pf[half * 2 + c] = pu.v;
            }
        }

        // O^T += V^T · P^T
#pragma unroll
        for (int dh = 0; dh < 2; ++dh)
#pragma unroll
            for (int c = 0; c < 4; ++c)
                oacc[dh] = mfma32(vf[dh][c], pf[c], oacc[dh]);

        __syncthreads();  // drains stage DMA (vmcnt) + protects buffer reuse
    }

    // epilogue: O/l + residual.  d_local = (reg&3) + 8*(reg>>2) + 4*l5
    const float inv = 1.0f / l;
    const size_t rowoff = (size_t)(b * 2048 + q0 + l31) * 1024 + h * 64;
#pragma unroll
    for (int dh = 0; dh < 2; ++dh) {
#pragma unroll
        for (int g = 0; g < 4; ++g) {
            const int col = dh * 32 + g * 8 + l5 * 4;
            f32x4 rv = *(const f32x4*)&res[rowoff + col];
            f32x4 ov;
#pragma unroll
            for (int r = 0; r < 4; ++r) ov[r] = oacc[dh][g * 4 + r] * inv + rv[r];
            *(f32x4*)&out[rowoff + col] = ov;
        }
    }
}

// ---------------- host ----------------
extern "C" void kernel_launch(void* const* d_in, const int* in_sizes, int n_in,
                              void* d_out, int out_size, void* d_ws, size_t ws_size,
                              hipStream_t stream) {
    const float* x      = (const float*)d_in[0];
    const float* feat   = (const float*)d_in[1];
    const float* norm_g = (const float*)d_in[2];
    const float* norm_b = (const float*)d_in[3];
    const float* W_cq   = (const float*)d_in[4];
    const float* W_ckv  = (const float*)d_in[5];
    const float* W_sqkv = (const float*)d_in[6];
    const float* ffn_g  = (const float*)d_in[7];
    const float* ffn_b  = (const float*)d_in[8];
    const float* W1     = (const float*)d_in[9];
    const float* b1     = (const float*)d_in[10];
    const float* W2     = (const float*)d_in[11];
    const float* b2     = (const float*)d_in[12];
    float* out = (float*)d_out;

    char* ws = (char*)d_ws;
    unsigned short* wq_t   = (unsigned short*)(ws + (size_t)(0u)   * (1u << 20));  // 2MB
    unsigned short* wkv_t  = (unsigned short*)(ws + (size_t)(2u)   * (1u << 20));  // 1.5MB
    unsigned short* wqkv_t = (unsigned short*)(ws + (size_t)(4u)   * (1u << 20));  // 6MB
    unsigned short* w1_t   = (unsigned short*)(ws + (size_t)(10u)  * (1u << 20));  // 8MB
    unsigned short* w2_t   = (unsigned short*)(ws + (size_t)(18u)  * (1u << 20));  // 8MB
    unsigned short* featb  = (unsigned short*)(ws + (size_t)(26u)  * (1u << 20));  // 3MB
    unsigned short* t0     = (unsigned short*)(ws + (size_t)(29u)  * (1u << 20));  // 8MB
    float*          cross  = (float*)        (ws + (size_t)(37u)  * (1u << 20));   // 16MB
    unsigned short* qb     = (unsigned short*)(ws + (size_t)(53u)  * (1u << 20));  // 8MB
    unsigned short* kvb    = (unsigned short*)(ws + (size_t)(61u)  * (1u << 20));  // 16MB
    unsigned short* qkvb   = (unsigned short*)(ws + (size_t)(77u)  * (1u << 20));  // 24MB
    unsigned short* vtb    = (unsigned short*)(ws + (size_t)(101u) * (1u << 20));  // 8MB
    unsigned short* h1     = (unsigned short*)(ws + (size_t)(53u)  * (1u << 20));  // 32MB (aliases q/kv/qkv, dead by FFN)

    // weights -> bf16 transposed [N,K]
    wconv_t<<<dim3(1024 / 32, 1024 / 32), 256, 0, stream>>>(W_cq,   wq_t,   1024, 1024);
    wconv_t<<<dim3(384 / 32,  2048 / 32), 256, 0, stream>>>(W_ckv,  wkv_t,  384,  2048);
    wconv_t<<<dim3(1024 / 32, 3072 / 32), 256, 0, stream>>>(W_sqkv, wqkv_t, 1024, 3072);
    wconv_t<<<dim3(1024 / 32, 4096 / 32), 256, 0, stream>>>(W1,     w1_t,   1024, 4096);
    wconv_t<<<dim3(4096 / 32, 1024 / 32), 256, 0, stream>>>(W2,     w2_t,   4096, 1024);
    fconv<<<dim3((4096 * 384 / 4) / 256), 256, 0, stream>>>(feat, featb, 4096 * 384 / 4);

    // ---- cross attention ----
    lnorm<<<4096, 256, 0, stream>>>(x, norm_g, norm_b, t0);
    // q: 4096x1024 @ K=1024, 128^2 tiles -> 256 blocks
    gemm8<2, 2, 4, 4, 0, true ><<<256, 256, 0, stream>>>(t0,    wq_t,  qb,  nullptr, nullptr, 4096, 1024, 1024, 1024);
    // kv: 4096x2048 @ K=384, 128^2 tiles -> 512 blocks
    gemm8<2, 2, 4, 4, 0, false><<<512, 256, 0, stream>>>(featb, wkv_t, kvb, nullptr, nullptr, 4096, 2048, 384,  0);
    vtrans<<<dim3(32, 32), 256, 0, stream>>>(kvb, vtb, 2048, 1024);
    attn<<<512, 256, 0, stream>>>(qb, 1024, 0, kvb, 2048, 0, vtb, x, cross);

    // ---- self attention ----
    lnorm<<<4096, 256, 0, stream>>>(cross, norm_g, norm_b, t0);
    // qkv: 4096x3072 @ K=1024, 256^2 tiles -> 192 blocks
    gemm8<2, 4, 8, 4, 0, true ><<<192, 512, 0, stream>>>(t0, wqkv_t, qkvb, nullptr, nullptr, 4096, 3072, 1024, 1024);
    vtrans<<<dim3(32, 32), 256, 0, stream>>>(qkvb, vtb, 3072, 2048);
    attn<<<512, 256, 0, stream>>>(qkvb, 3072, 0, qkvb, 3072, 1024, vtb, cross, out);

    // ---- FFN ----
    lnorm<<<4096, 256, 0, stream>>>(out, ffn_g, ffn_b, t0);
    // W1: 4096x4096 @ K=1024, 256^2 tiles -> 256 blocks, GELU epilogue
    gemm8<2, 4, 8, 4, 1, false><<<256, 512, 0, stream>>>(t0, w1_t, h1, b1, nullptr, 4096, 4096, 1024, 0);
    // W2: 4096x1024 @ K=4096, 128^2 tiles -> 256 blocks, bias+residual f32 epilogue
    gemm8<2, 2, 4, 4, 2, false><<<256, 256, 0, stream>>>(h1, w2_t, out, b2, (const float*)out, 4096, 1024, 4096, 0);
}

// Round 5
// 349.347 us; speedup vs baseline: 1.5385x; 1.0459x over previous
//
#include <hip/hip_runtime.h>
#include <math.h>
#include <stdint.h>

typedef __attribute__((ext_vector_type(8)))  short   short8;
typedef __attribute__((ext_vector_type(4)))  short   short4v;
typedef __attribute__((ext_vector_type(8)))  __bf16  bf16x8;
typedef __attribute__((ext_vector_type(4)))  float   f32x4;
typedef __attribute__((ext_vector_type(16))) float   f32x16;

__device__ __forceinline__ unsigned short f2b(float f) {
    union { float f; unsigned u; } v; v.f = f;
    unsigned r = v.u + 0x7FFF + ((v.u >> 16) & 1);
    return (unsigned short)(r >> 16);
}

__device__ __forceinline__ f32x4 mfma_bf16(bf16x8 a, bf16x8 b, f32x4 c) {
    return __builtin_amdgcn_mfma_f32_16x16x32_bf16(a, b, c, 0, 0, 0);
}

__device__ __forceinline__ f32x16 mfma32(bf16x8 a, bf16x8 b, f32x16 c) {
    return __builtin_amdgcn_mfma_f32_32x32x16_bf16(a, b, c, 0, 0, 0);
}

__device__ __forceinline__ unsigned cvt_pk_bf16(float lo, float hi) {
    unsigned r;
    asm volatile("v_cvt_pk_bf16_f32 %0, %1, %2" : "=v"(r) : "v"(lo), "v"(hi));
    return r;
}

__device__ __forceinline__ void gload_lds16(const unsigned short* g, unsigned short* l) {
    __builtin_amdgcn_global_load_lds(
        (const __attribute__((address_space(1))) void*)g,
        (__attribute__((address_space(3))) void*)l,
        16, 0, 0);
}

template <int N>
__device__ __forceinline__ void wait_vmcnt() {
    if constexpr (N == 0)       asm volatile("s_waitcnt vmcnt(0)" ::: "memory");
    else if constexpr (N == 6)  asm volatile("s_waitcnt vmcnt(6)" ::: "memory");
    else if constexpr (N == 8)  asm volatile("s_waitcnt vmcnt(8)" ::: "memory");
    else                        static_assert(N == 0 || N == 6 || N == 8, "add vmcnt case");
}

// 0.125 (d_head^-0.5) * log2(e): softmax computed in base-2 (exact rescale)
#define QSCALE 0.18033688011112042592f

// ---------------- weight transpose + f32->bf16 ----------------
__global__ __launch_bounds__(256) void wconv_t(const float* __restrict__ W,
                                               unsigned short* __restrict__ Wt,
                                               int K, int N) {
    __shared__ float tile[32][33];
    int bk = blockIdx.x * 32;
    int bn = blockIdx.y * 32;
    int tx = threadIdx.x & 31, ty = threadIdx.x >> 5;  // 32 x 8
#pragma unroll
    for (int i = 0; i < 4; ++i) {
        int r = ty + i * 8;
        tile[r][tx] = W[(size_t)(bk + r) * N + bn + tx];
    }
    __syncthreads();
#pragma unroll
    for (int i = 0; i < 4; ++i) {
        int r = ty + i * 8;
        Wt[(size_t)(bn + r) * K + bk + tx] = f2b(tile[tx][r]);
    }
}

// ---------------- f32 -> bf16 elementwise (x4) ----------------
__global__ __launch_bounds__(256) void fconv(const float* __restrict__ in,
                                             unsigned short* __restrict__ out, int n4) {
    int i = blockIdx.x * 256 + threadIdx.x;
    if (i >= n4) return;
    f32x4 v = ((const f32x4*)in)[i];
    short4v o;
    o.x = (short)f2b(v.x); o.y = (short)f2b(v.y);
    o.z = (short)f2b(v.z); o.w = (short)f2b(v.w);
    ((short4v*)out)[i] = o;
}

// ---------------- layernorm (C=1024), f32 in -> bf16 out ----------------
__global__ __launch_bounds__(256) void lnorm(const float* __restrict__ x,
                                             const float* __restrict__ g,
                                             const float* __restrict__ bta,
                                             unsigned short* __restrict__ out) {
    int row = blockIdx.x;
    const f32x4* xr = (const f32x4*)(x + (size_t)row * 1024);
    int t = threadIdx.x;
    f32x4 v = xr[t];
    float s  = v.x + v.y + v.z + v.w;
    float s2 = v.x * v.x + v.y * v.y + v.z * v.z + v.w * v.w;
#pragma unroll
    for (int m = 1; m < 64; m <<= 1) {
        s  += __shfl_xor(s, m);
        s2 += __shfl_xor(s2, m);
    }
    __shared__ float rs[8];
    int w = t >> 6;
    if ((t & 63) == 0) { rs[w] = s; rs[4 + w] = s2; }
    __syncthreads();
    s  = rs[0] + rs[1] + rs[2] + rs[3];
    s2 = rs[4] + rs[5] + rs[6] + rs[7];
    float mean = s * (1.0f / 1024.0f);
    float var  = s2 * (1.0f / 1024.0f) - mean * mean;
    float rstd = rsqrtf(var + 1e-5f);
    f32x4 gv = ((const f32x4*)g)[t];
    f32x4 bv = ((const f32x4*)bta)[t];
    short4v o;
    o.x = (short)f2b((v.x - mean) * rstd * gv.x + bv.x);
    o.y = (short)f2b((v.y - mean) * rstd * gv.y + bv.y);
    o.z = (short)f2b((v.z - mean) * rstd * gv.z + bv.z);
    o.w = (short)f2b((v.w - mean) * rstd * gv.w + bv.w);
    ((short4v*)(out + (size_t)row * 1024))[t] = o;
}

// ---------------- pipelined GEMM: A[M,K] x Bt[N,K] -> C[M,N], BK=64 ----------------
// Counted-vmcnt double-buffer (T3/T4 depth-1): STAGE(next) -> vmcnt(L) -> barrier ->
// {ds_read + MFMA} x2 khalf -> barrier. T2 swizzle: source granule ^ (row&7) on
// stage, same XOR on ds_read (involution). setprio around MFMA clusters (T5).
// WM x WN waves, per-wave MI*16 rows x NI*16 cols. Tiles sized so grid >= 2 blocks/CU.
// EPI: 0 = bf16 out (+QSCALE on cols < scale_cols if SCQ)
//      1 = bf16 out, +bias, exact GELU
//      2 = f32 out, +bias, +f32 residual
template <int WM, int WN, int MI, int NI, int EPI, bool SCQ>
__global__ __launch_bounds__(WM * WN * 64, 2)
void gemm8(const unsigned short* __restrict__ A,
           const unsigned short* __restrict__ Bt,
           void* __restrict__ C,
           const float* __restrict__ bias,
           const float* __restrict__ resid,
           int M, int N, int K, int scale_cols) {
    constexpr int BM = WM * MI * 16;
    constexpr int BN = WN * NI * 16;
    constexpr int THREADS = WM * WN * 64;
    constexpr int ROWS = THREADS / 8;          // rows per stage instr
    constexpr int IA = BM / ROWS;              // stage instrs for A
    constexpr int IB = BN / ROWS;

    // bijective XCD swizzle (all grids are multiples of 8), m-major per XCD
    const int nwg = gridDim.x;
    const int nby = N / BN;
    int flat = blockIdx.x;
    int wk = (flat & 7) * (nwg >> 3) + (flat >> 3);
    const int m0 = (wk / nby) * BM;
    const int n0 = (wk % nby) * BN;

    __shared__ unsigned short As[2][BM * 64];
    __shared__ unsigned short Bs[2][BN * 64];

    const int tid  = threadIdx.x;
    const int lane = tid & 63;
    const int wid  = tid >> 6;
    const int wm = wid / WN, wn = wid % WN;
    const int l15 = lane & 15, q4 = lane >> 4, xw = lane & 7;

    const int sr = tid >> 3;                    // stage row within group
    const int sg = (tid & 7) ^ (sr & 7);        // swizzled source granule

    const unsigned short* ag = A  + (size_t)(m0 + sr) * K + sg * 8;
    const unsigned short* bg = Bt + (size_t)(n0 + sr) * K + sg * 8;

    f32x4 acc[MI][NI] = {};

    auto STAGE = [&](int d, int t) {
        const int k0 = t * 64;
#pragma unroll
        for (int i = 0; i < IA; ++i)
            gload_lds16(ag + (size_t)(i * ROWS) * K + k0, &As[d][i * ROWS * 64 + tid * 8]);
#pragma unroll
        for (int i = 0; i < IB; ++i)
            gload_lds16(bg + (size_t)(i * ROWS) * K + k0, &Bs[d][i * ROWS * 64 + tid * 8]);
    };

    const int NT = K >> 6;
    STAGE(0, 0);

    for (int t = 0; t < NT; ++t) {
        const int c = t & 1;
        if (t + 1 < NT) STAGE(c ^ 1, t + 1);
        __builtin_amdgcn_sched_barrier(0);
        if (t + 1 < NT) wait_vmcnt<IA + IB>();
        else            wait_vmcnt<0>();
        __builtin_amdgcn_s_barrier();
        __builtin_amdgcn_sched_barrier(0);
#pragma unroll
        for (int h = 0; h < 2; ++h) {
            bf16x8 a[MI], b[NI];
            const int gsl = h * 4 + q4;         // granule before swizzle
#pragma unroll
            for (int mi = 0; mi < MI; ++mi)
                a[mi] = *(const bf16x8*)&As[c][(wm * MI * 16 + mi * 16 + l15) * 64 + ((gsl ^ xw) << 3)];
#pragma unroll
            for (int ni = 0; ni < NI; ++ni)
                b[ni] = *(const bf16x8*)&Bs[c][(wn * NI * 16 + ni * 16 + l15) * 64 + ((gsl ^ xw) << 3)];
            __builtin_amdgcn_s_setprio(1);
#pragma unroll
            for (int mi = 0; mi < MI; ++mi)
#pragma unroll
                for (int ni = 0; ni < NI; ++ni)
                    acc[mi][ni] = mfma_bf16(a[mi], b[ni], acc[mi][ni]);
            __builtin_amdgcn_s_setprio(0);
        }
        __builtin_amdgcn_sched_barrier(0);
        __builtin_amdgcn_s_barrier();
    }

    // epilogue
    const int rb = m0 + wm * MI * 16 + q4 * 4;
    const int cb = n0 + wn * NI * 16 + l15;
    float bv[NI];
    if (EPI >= 1) {
#pragma unroll
        for (int ni = 0; ni < NI; ++ni) bv[ni] = bias[cb + ni * 16];
    }
#pragma unroll
    for (int mi = 0; mi < MI; ++mi) {
#pragma unroll
        for (int r = 0; r < 4; ++r) {
            const int row = rb + mi * 16 + r;
#pragma unroll
            for (int ni = 0; ni < NI; ++ni) {
                const int col = cb + ni * 16;
                float v = acc[mi][ni][r];
                if (EPI == 0) {
                    if (SCQ && col < scale_cols) v *= QSCALE;
                    ((unsigned short*)C)[(size_t)row * N + col] = f2b(v);
                } else if (EPI == 1) {
                    v += bv[ni];
                    v = 0.5f * v * (1.0f + erff(v * 0.70710678118f));
                    ((unsigned short*)C)[(size_t)row * N + col] = f2b(v);
                } else {
                    v += bv[ni] + resid[(size_t)row * N + col];
                    ((float*)C)[(size_t)row * N + col] = v;
                }
            }
        }
    }
}

// ---------------- V transpose: [b,n, col_off + h*64 + d] -> Vt[bh][d][n] ----------------
__global__ __launch_bounds__(256) void vtrans(const unsigned short* __restrict__ src,
                                              unsigned short* __restrict__ dst,
                                              int src_stride, int col_off) {
    int n0 = blockIdx.x * 64;
    int bh = blockIdx.y;
    int b = bh >> 4, h = bh & 15;
    __shared__ unsigned short t[64][65];
    int tx = threadIdx.x & 63, ty = threadIdx.x >> 6;  // 64 x 4
    const unsigned short* s = src + (size_t)(b * 2048 + n0) * src_stride + col_off + h * 64;
#pragma unroll
    for (int i = 0; i < 16; ++i) {
        int n = ty * 16 + i;
        t[n][tx] = s[(size_t)n * src_stride + tx];
    }
    __syncthreads();
    unsigned short* d = dst + (size_t)bh * 64 * 2048 + n0;
#pragma unroll
    for (int i = 0; i < 16; ++i) {
        int dd = ty * 16 + i;
        d[(size_t)dd * 2048 + tx] = t[tx][dd];
    }
}

// ---------------- flash attention, swapped-operand 32x32, LDS-staged K/V ----------------
__global__ __launch_bounds__(256) void attn(const unsigned short* __restrict__ Q, int q_stride, int q_off,
                                            const unsigned short* __restrict__ Kp, int k_stride, int k_off,
                                            const unsigned short* __restrict__ Vt,
                                            const float* __restrict__ res,
                                            float* __restrict__ out) {
    // 512 blocks; XCD = bid%8 gets 4 bh values -> K/V (2MB) L2-resident per XCD
    const int bid = blockIdx.x;
    const int slot = bid >> 3;
    const int bh = (bid & 7) * 4 + (slot >> 4);
    const int qt = slot & 15;
    const int b = bh >> 4, h = bh & 15;
    const int lane = threadIdx.x & 63, w = threadIdx.x >> 6;
    const int l31 = lane & 31, l5 = lane >> 5;

    __shared__ unsigned short Ks[2][64 * 64];
    __shared__ unsigned short Vs[2][64 * 64];

    const int q0 = qt * 128 + w * 32;

    // Q fragments (B-operand): col q = l31, d = i*16 + l5*8 + j
    const unsigned short* qp = Q + (size_t)(b * 2048 + q0 + l31) * q_stride + q_off + h * 64 + l5 * 8;
    bf16x8 qf[4];
#pragma unroll
    for (int i = 0; i < 4; ++i) qf[i] = *(const bf16x8*)&qp[i * 16];

    const unsigned short* kg = Kp + (size_t)(b * 2048) * k_stride + k_off + h * 64;
    const unsigned short* vg = Vt + (size_t)bh * 64 * 2048;

    const int sgrow = lane >> 3;                          // row within 8-row group
    const int sgcol = (((lane & 7) ^ sgrow) << 3);        // element col (16B granule XOR)

    f32x16 oacc[2] = {};
    float m = -1e30f, l = 0.f;

    const int kxor = (l31 & 7) << 3;   // read-side XOR (elements)

    // ---- prologue: stage tile 0 ----
#pragma unroll
    for (int t8 = 0; t8 < 2; ++t8) {
        const int rb = w * 16 + t8 * 8;
        gload_lds16(kg + (size_t)(rb + sgrow) * k_stride + sgcol, &Ks[0][rb * 64]);
        gload_lds16(vg + (size_t)(rb + sgrow) * 2048 + sgcol,     &Vs[0][rb * 64]);
    }
    __syncthreads();

    for (int t = 0; t < 32; ++t) {
        const int cur = t & 1;
        if (t + 1 < 32) {
            const int n1 = (t + 1) * 64;
#pragma unroll
            for (int t8 = 0; t8 < 2; ++t8) {
                const int rb = w * 16 + t8 * 8;
                gload_lds16(kg + (size_t)(n1 + rb + sgrow) * k_stride + sgcol, &Ks[cur ^ 1][rb * 64]);
                gload_lds16(vg + (size_t)(rb + sgrow) * 2048 + n1 + sgcol,     &Vs[cur ^ 1][rb * 64]);
            }
        }

        // K fragments (A-operand): row k = ks*32 + l31, d = i*16 + l5*8 + j
        bf16x8 kf[2][4];
#pragma unroll
        for (int ks = 0; ks < 2; ++ks)
#pragma unroll
            for (int i = 0; i < 4; ++i)
                kf[ks][i] = *(const bf16x8*)&Ks[cur][(ks * 32 + l31) * 64 + ((i * 16 + l5 * 8) ^ kxor)];

        f32x16 s0 = {}, s1 = {};
#pragma unroll
        for (int i = 0; i < 4; ++i) s0 = mfma32(kf[0][i], qf[i], s0);
#pragma unroll
        for (int i = 0; i < 4; ++i) s1 = mfma32(kf[1][i], qf[i], s1);

        // V fragments (A-operand): row d = dh*32 + l31, k = c*16 + l5*8 + j
        bf16x8 vf[2][4];
#pragma unroll
        for (int dh = 0; dh < 2; ++dh)
#pragma unroll
            for (int c = 0; c < 4; ++c)
                vf[dh][c] = *(const bf16x8*)&Vs[cur][(dh * 32 + l31) * 64 + ((c * 16 + l5 * 8) ^ kxor)];

        // online softmax (base-2, q lane-local)
        float mx = s0[0];
#pragma unroll
        for (int r = 1; r < 16; ++r) mx = fmaxf(mx, s0[r]);
#pragma unroll
        for (int r = 0; r < 16; ++r) mx = fmaxf(mx, s1[r]);
        mx = fmaxf(mx, __shfl_xor(mx, 32));
        if (!__all(mx - m <= 8.f)) {  // defer-max (T13)
            float mnew = fmaxf(m, mx);
            float al = __builtin_amdgcn_exp2f(m - mnew);
            m = mnew;
            l *= al;
#pragma unroll
            for (int dh = 0; dh < 2; ++dh)
#pragma unroll
                for (int r = 0; r < 16; ++r) oacc[dh][r] *= al;
        }
        float p0[16], p1[16];
        float ssum = 0.f;
#pragma unroll
        for (int r = 0; r < 16; ++r) { p0[r] = __builtin_amdgcn_exp2f(s0[r] - m); ssum += p0[r]; }
#pragma unroll
        for (int r = 0; r < 16; ++r) { p1[r] = __builtin_amdgcn_exp2f(s1[r] - m); ssum += p1[r]; }
        ssum += __shfl_xor(ssum, 32);
        l += ssum;

        // P^T -> B-operand fragments via cvt_pk + permlane32_swap (T12)
        bf16x8 pf[4];
#pragma unroll
        for (int half = 0; half < 2; ++half) {
            const float* p = half ? p1 : p0;
#pragma unroll
            for (int c = 0; c < 2; ++c) {
                unsigned a0 = cvt_pk_bf16(p[8 * c + 0], p[8 * c + 1]);
                unsigned a1 = cvt_pk_bf16(p[8 * c + 4], p[8 * c + 5]);
                unsigned b0 = cvt_pk_bf16(p[8 * c + 2], p[8 * c + 3]);
                unsigned b1 = cvt_pk_bf16(p[8 * c + 6], p[8 * c + 7]);
                asm volatile("v_permlane32_swap_b32 %0, %1" : "+v"(a0), "+v"(a1));
                asm volatile("v_permlane32_swap_b32 %0, %1" : "+v"(b0), "+v"(b1));
                union { unsigned u[4]; bf16x8 v; } pu;
                pu.u[0] = a0; pu.u[1] = b0; pu.u[2] = a1; pu.u[3] = b1;
                pf[half * 2 + c] = pu.v;
            }
        }

        // O^T += V^T · P^T
#pragma unroll
        for (int dh = 0; dh < 2; ++dh)
#pragma unroll
            for (int c = 0; c < 4; ++c)
                oacc[dh] = mfma32(vf[dh][c], pf[c], oacc[dh]);

        __syncthreads();  // drains stage DMA (vmcnt) + protects buffer reuse
    }

    // epilogue: O/l + residual.  d_local = (reg&3) + 8*(reg>>2) + 4*l5
    const float inv = 1.0f / l;
    const size_t rowoff = (size_t)(b * 2048 + q0 + l31) * 1024 + h * 64;
#pragma unroll
    for (int dh = 0; dh < 2; ++dh) {
#pragma unroll
        for (int g = 0; g < 4; ++g) {
            const int col = dh * 32 + g * 8 + l5 * 4;
            f32x4 rv = *(const f32x4*)&res[rowoff + col];
            f32x4 ov;
#pragma unroll
            for (int r = 0; r < 4; ++r) ov[r] = oacc[dh][g * 4 + r] * inv + rv[r];
            *(f32x4*)&out[rowoff + col] = ov;
        }
    }
}

// ---------------- host ----------------
extern "C" void kernel_launch(void* const* d_in, const int* in_sizes, int n_in,
                              void* d_out, int out_size, void* d_ws, size_t ws_size,
                              hipStream_t stream) {
    const float* x      = (const float*)d_in[0];
    const float* feat   = (const float*)d_in[1];
    const float* norm_g = (const float*)d_in[2];
    const float* norm_b = (const float*)d_in[3];
    const float* W_cq   = (const float*)d_in[4];
    const float* W_ckv  = (const float*)d_in[5];
    const float* W_sqkv = (const float*)d_in[6];
    const float* ffn_g  = (const float*)d_in[7];
    const float* ffn_b  = (const float*)d_in[8];
    const float* W1     = (const float*)d_in[9];
    const float* b1     = (const float*)d_in[10];
    const float* W2     = (const float*)d_in[11];
    const float* b2     = (const float*)d_in[12];
    float* out = (float*)d_out;

    char* ws = (char*)d_ws;
    unsigned short* wq_t   = (unsigned short*)(ws + (size_t)(0u)   * (1u << 20));  // 2MB
    unsigned short* wkv_t  = (unsigned short*)(ws + (size_t)(2u)   * (1u << 20));  // 1.5MB
    unsigned short* wqkv_t = (unsigned short*)(ws + (size_t)(4u)   * (1u << 20));  // 6MB
    unsigned short* w1_t   = (unsigned short*)(ws + (size_t)(10u)  * (1u << 20));  // 8MB
    unsigned short* w2_t   = (unsigned short*)(ws + (size_t)(18u)  * (1u << 20));  // 8MB
    unsigned short* featb  = (unsigned short*)(ws + (size_t)(26u)  * (1u << 20));  // 3MB
    unsigned short* t0     = (unsigned short*)(ws + (size_t)(29u)  * (1u << 20));  // 8MB
    float*          cross  = (float*)        (ws + (size_t)(37u)  * (1u << 20));   // 16MB
    unsigned short* qb     = (unsigned short*)(ws + (size_t)(53u)  * (1u << 20));  // 8MB
    unsigned short* kvb    = (unsigned short*)(ws + (size_t)(61u)  * (1u << 20));  // 16MB
    unsigned short* qkvb   = (unsigned short*)(ws + (size_t)(77u)  * (1u << 20));  // 24MB
    unsigned short* vtb    = (unsigned short*)(ws + (size_t)(101u) * (1u << 20));  // 8MB
    unsigned short* h1     = (unsigned short*)(ws + (size_t)(53u)  * (1u << 20));  // 32MB (aliases q/kv/qkv, dead by FFN)

    // weights -> bf16 transposed [N,K]
    wconv_t<<<dim3(1024 / 32, 1024 / 32), 256, 0, stream>>>(W_cq,   wq_t,   1024, 1024);
    wconv_t<<<dim3(384 / 32,  2048 / 32), 256, 0, stream>>>(W_ckv,  wkv_t,  384,  2048);
    wconv_t<<<dim3(1024 / 32, 3072 / 32), 256, 0, stream>>>(W_sqkv, wqkv_t, 1024, 3072);
    wconv_t<<<dim3(1024 / 32, 4096 / 32), 256, 0, stream>>>(W1,     w1_t,   1024, 4096);
    wconv_t<<<dim3(4096 / 32, 1024 / 32), 256, 0, stream>>>(W2,     w2_t,   4096, 1024);
    fconv<<<dim3((4096 * 384 / 4) / 256), 256, 0, stream>>>(feat, featb, 4096 * 384 / 4);

    // ---- cross attention ----
    lnorm<<<4096, 256, 0, stream>>>(x, norm_g, norm_b, t0);
    // q: 4096x1024 @ K=1024, 128x64 tiles -> 512 blocks (2/CU)
    gemm8<2, 2, 4, 2, 0, true ><<<512, 256, 0, stream>>>(t0,    wq_t,  qb,  nullptr, nullptr, 4096, 1024, 1024, 1024);
    // kv: 4096x2048 @ K=384, 128^2 tiles -> 512 blocks (2/CU)
    gemm8<2, 2, 4, 4, 0, false><<<512, 256, 0, stream>>>(featb, wkv_t, kvb, nullptr, nullptr, 4096, 2048, 384,  0);
    vtrans<<<dim3(32, 32), 256, 0, stream>>>(kvb, vtb, 2048, 1024);
    attn<<<512, 256, 0, stream>>>(qb, 1024, 0, kvb, 2048, 0, vtb, x, cross);

    // ---- self attention ----
    lnorm<<<4096, 256, 0, stream>>>(cross, norm_g, norm_b, t0);
    // qkv: 4096x3072 @ K=1024, 128x64 tiles -> 1536 blocks (3/CU, 2 rounds)
    gemm8<2, 2, 4, 2, 0, true ><<<1536, 256, 0, stream>>>(t0, wqkv_t, qkvb, nullptr, nullptr, 4096, 3072, 1024, 1024);
    vtrans<<<dim3(32, 32), 256, 0, stream>>>(qkvb, vtb, 3072, 2048);
    attn<<<512, 256, 0, stream>>>(qkvb, 3072, 0, qkvb, 3072, 1024, vtb, cross, out);

    // ---- FFN ----
    lnorm<<<4096, 256, 0, stream>>>(out, ffn_g, ffn_b, t0);
    // W1: 4096x4096 @ K=1024, 128^2 tiles -> 1024 blocks (2/CU, 2 rounds), GELU epilogue
    gemm8<2, 2, 4, 4, 1, false><<<1024, 256, 0, stream>>>(t0, w1_t, h1, b1, nullptr, 4096, 4096, 1024, 0);
    // W2: 4096x1024 @ K=4096, 128x64 tiles -> 512 blocks (2/CU), bias+residual f32 epilogue
    gemm8<2, 2, 4, 2, 2, false><<<512, 256, 0, stream>>>(h1, w2_t, out, b2, (const float*)out, 4096, 1024, 4096, 0);
}